// Round 1
// baseline (923.071 us; speedup 1.0000x reference)
//
#include <hip/hip_runtime.h>
#include <hip/hip_bf16.h>

#define B_ 2
#define S_ 1024
#define D_ 768
#define H_ 12
#define HD_ 64
#define FF_ 3072
#define E_ 32768

typedef short bf16x8 __attribute__((ext_vector_type(8)));
typedef float f32x4 __attribute__((ext_vector_type(4)));

__device__ __forceinline__ unsigned short f2bf(float f) {
    __hip_bfloat16 h = __float2bfloat16(f);
    return __builtin_bit_cast(unsigned short, h);
}
__device__ __forceinline__ float gelu_exact(float x) {
    return 0.5f * x * (1.0f + erff(x * 0.70710678118654752f));
}

// ---------------- LayerNorm: f32 in -> bf16 out (row = 768) ----------------
__global__ __launch_bounds__(256) void ln_kernel(
    const float* __restrict__ x, const float* __restrict__ g,
    const float* __restrict__ b, unsigned short* __restrict__ out)
{
    const int row = blockIdx.x;
    const int t = threadIdx.x;
    const float* xr = x + (size_t)row * D_;
    float v0 = xr[t], v1 = xr[t + 256], v2 = xr[t + 512];
    float s = v0 + v1 + v2, s2 = v0 * v0 + v1 * v1 + v2 * v2;
    for (int m = 32; m; m >>= 1) { s += __shfl_xor(s, m); s2 += __shfl_xor(s2, m); }
    __shared__ float red[8];
    const int w = t >> 6;
    if ((t & 63) == 0) { red[w] = s; red[4 + w] = s2; }
    __syncthreads();
    s = red[0] + red[1] + red[2] + red[3];
    s2 = red[4] + red[5] + red[6] + red[7];
    const float mean = s * (1.f / D_);
    const float var = s2 * (1.f / D_) - mean * mean;
    const float rstd = rsqrtf(var + 1e-5f);
    unsigned short* orow = out + (size_t)row * D_;
    orow[t]       = f2bf((v0 - mean) * rstd * g[t]       + b[t]);
    orow[t + 256] = f2bf((v1 - mean) * rstd * g[t + 256] + b[t + 256]);
    orow[t + 512] = f2bf((v2 - mean) * rstd * g[t + 512] + b[t + 512]);
}

// ------------- weight transpose+convert: W[K][N] f32 -> Wt[N][K] bf16 -------------
__global__ __launch_bounds__(256) void wtrans_kernel(
    const float* __restrict__ W, unsigned short* __restrict__ Wt, int K, int N)
{
    __shared__ float tile[32][33];
    const int tx = threadIdx.x & 31, ty = threadIdx.x >> 5;  // ty 0..7
    const int nb = blockIdx.x * 32, kb = blockIdx.y * 32;
    for (int r = 0; r < 32; r += 8)
        tile[ty + r][tx] = W[(size_t)(kb + ty + r) * N + nb + tx];
    __syncthreads();
    for (int r = 0; r < 32; r += 8)
        Wt[(size_t)(nb + ty + r) * K + kb + tx] = f2bf(tile[tx][ty + r]);
}

// ---------------- bf16 MFMA GEMM: C[M][N] = A[M][K] @ Bt[N][K]^T + bias ----------------
// 64x64 tile, BK=32, 4 waves (2x2), each wave 32x32 via 2x2 MFMA 16x16x32.
template<bool GELU, bool RES, bool OUTBF>
__global__ __launch_bounds__(256) void gemm_kernel(
    const unsigned short* __restrict__ A, const unsigned short* __restrict__ Bt,
    const float* __restrict__ bias, const float* __restrict__ res,
    void* __restrict__ outp, int M, int N, int K)
{
    __shared__ unsigned short As[64][40];  // +8 pad: 20-dword stride -> 2-way (free)
    __shared__ unsigned short Bs[64][40];
    const int m0 = blockIdx.y * 64, n0 = blockIdx.x * 64;
    const int t = threadIdx.x;
    const int w = t >> 6, l = t & 63;
    const int wm = w >> 1, wn = w & 1;
    const int r = l & 15, g = l >> 4;
    const int srow = t >> 2, sseg = t & 3;
    f32x4 acc[2][2] = {};
    for (int k0 = 0; k0 < K; k0 += 32) {
        __syncthreads();
        const uint4 av = *reinterpret_cast<const uint4*>(A + (size_t)(m0 + srow) * K + k0 + sseg * 8);
        *reinterpret_cast<uint4*>(&As[srow][sseg * 8]) = av;
        const uint4 bv = *reinterpret_cast<const uint4*>(Bt + (size_t)(n0 + srow) * K + k0 + sseg * 8);
        *reinterpret_cast<uint4*>(&Bs[srow][sseg * 8]) = bv;
        __syncthreads();
        bf16x8 af[2], bfr[2];
        af[0]  = *reinterpret_cast<const bf16x8*>(&As[wm * 32 + r][g * 8]);
        af[1]  = *reinterpret_cast<const bf16x8*>(&As[wm * 32 + 16 + r][g * 8]);
        bfr[0] = *reinterpret_cast<const bf16x8*>(&Bs[wn * 32 + r][g * 8]);
        bfr[1] = *reinterpret_cast<const bf16x8*>(&Bs[wn * 32 + 16 + r][g * 8]);
        for (int m = 0; m < 2; m++)
            for (int n = 0; n < 2; n++)
                acc[m][n] = __builtin_amdgcn_mfma_f32_16x16x32_bf16(af[m], bfr[n], acc[m][n], 0, 0, 0);
    }
    for (int m = 0; m < 2; m++)
        for (int n = 0; n < 2; n++) {
            const int col = n0 + wn * 32 + n * 16 + r;
            const float bvv = bias[col];
            for (int j = 0; j < 4; j++) {
                const int row = m0 + wm * 32 + m * 16 + g * 4 + j;
                float v = acc[m][n][j] + bvv;
                if (RES) v += res[(size_t)row * N + col];
                if (GELU) v = gelu_exact(v);
                if (OUTBF) ((unsigned short*)outp)[(size_t)row * N + col] = f2bf(v);
                else       ((float*)outp)[(size_t)row * N + col] = v;
            }
        }
}

// ---------------- edge-attr per-head MLP: proj[e][h] ----------------
__global__ __launch_bounds__(256) void edge_proj_kernel(
    const float* __restrict__ ea, const float* __restrict__ W1, const float* __restrict__ b1,
    const float* __restrict__ W2, const float* __restrict__ b2, float* __restrict__ proj)
{
    const int tid = blockIdx.x * 256 + threadIdx.x;  // E_*H_ = 393216
    const int e = tid / H_, h = tid - e * H_;
    const float a = ea[e];
    float s = 0.f;
    for (int j = 0; j < 16; j++) {
        const float tv = a * W1[h * 16 + j] + b1[h * 16 + j];
        s += gelu_exact(tv) * W2[h * 16 + j];
    }
    proj[tid] = s + b2[h];
}

// last-write-wins scatter: winner[src*S+dst] = max edge idx
__global__ __launch_bounds__(256) void scatter_kernel(const int* __restrict__ ei, int* __restrict__ winner)
{
    const int e = blockIdx.x * 256 + threadIdx.x;  // 32768
    const int s = ei[e], d = ei[E_ + e];
    atomicMax(&winner[s * S_ + d], e);
}

// detect adj_mask storage: uint8 (flag=1) vs int32 (flag=0)
__global__ __launch_bounds__(256) void detect_kernel(const unsigned char* __restrict__ m, int* __restrict__ flag)
{
    const int i = blockIdx.x * 256 + threadIdx.x;  // 65536 probes, bytes at 4i+1 (safe both layouts)
    const unsigned char bval = m[i * 4 + 1];
    unsigned long long bl = __ballot(bval != 0);
    if ((threadIdx.x & 63) == 0 && bl) atomicOr(flag, 1);
}

// ---------------- attention: one block = (b, h, 8 q-rows) ----------------
__global__ __launch_bounds__(256) void attn_kernel(
    const float* __restrict__ q, const float* __restrict__ k, const float* __restrict__ v,
    const void* __restrict__ adj, const int* __restrict__ fmtflag,
    const int* __restrict__ winner, const float* __restrict__ proj,
    unsigned short* __restrict__ outb)
{
    __shared__ float Qs[8][64];
    __shared__ float Ks[32][68];   // pad 64->68: 4-way max on strided reads
    __shared__ float Ss[8][1024];
    const int t = threadIdx.x;
    const int q0 = blockIdx.x * 8;
    const int h = blockIdx.y;
    const int b = blockIdx.z;
    const size_t base = ((size_t)b * S_) * D_ + h * HD_;
    for (int idx = t; idx < 512; idx += 256) {
        const int r = idx >> 6, c = idx & 63;
        Qs[r][c] = q[base + (size_t)(q0 + r) * D_ + c];
    }
    const int fmt = *fmtflag;
    const unsigned char* mu8 = (const unsigned char*)adj;
    const int* mi32 = (const int*)adj;
    const size_t mbase = (size_t)b * S_ * S_;
    const int rr = t >> 5, cc = t & 31;
    __syncthreads();
    // ---- scores ----
    for (int kt = 0; kt < S_; kt += 32) {
        for (int idx = t; idx < 2048; idx += 256) {
            const int kk = idx >> 6, c = idx & 63;
            Ks[kk][c] = k[base + (size_t)(kt + kk) * D_ + c];
        }
        __syncthreads();
        float dot = 0.f;
        const float4* q4 = reinterpret_cast<const float4*>(&Qs[rr][0]);
        const float4* k4 = reinterpret_cast<const float4*>(&Ks[cc][0]);
        for (int j = 0; j < 16; j++) {
            const float4 a = q4[j], bb = k4[j];
            dot += a.x * bb.x + a.y * bb.y + a.z * bb.z + a.w * bb.w;
        }
        const int kg = kt + cc, qg = q0 + rr;
        const bool msk = fmt ? (mu8[mbase + (size_t)qg * S_ + kg] != 0)
                             : (mi32[mbase + (size_t)qg * S_ + kg] != 0);
        float sval;
        if (msk) {
            const int e = winner[qg * S_ + kg];
            const float bvv = (e >= 0) ? proj[(size_t)e * H_ + h] : 0.f;
            sval = dot * 0.125f + bvv;
        } else sval = -1e9f;
        Ss[rr][kg] = sval;
        __syncthreads();
    }
    // ---- softmax (row rr handled by its own 32 lanes; each lane reads what it wrote) ----
    float mx = -3e38f;
    for (int kk = cc; kk < S_; kk += 32) mx = fmaxf(mx, Ss[rr][kk]);
    for (int m = 16; m; m >>= 1) mx = fmaxf(mx, __shfl_xor(mx, m));
    float sum = 0.f;
    for (int kk = cc; kk < S_; kk += 32) {
        const float p = expf(Ss[rr][kk] - mx);
        Ss[rr][kk] = p;
        sum += p;
    }
    for (int m = 16; m; m >>= 1) sum += __shfl_xor(sum, m);
    const float inv = 1.f / sum;
    __syncthreads();
    // ---- PV ----
    float a0 = 0.f, a1 = 0.f;
    for (int kt = 0; kt < S_; kt += 32) {
        for (int idx = t; idx < 2048; idx += 256) {
            const int kk = idx >> 6, c = idx & 63;
            Ks[kk][c] = v[base + (size_t)(kt + kk) * D_ + c];
        }
        __syncthreads();
        for (int kk = 0; kk < 32; kk++) {
            const float p = Ss[rr][kt + kk];
            a0 += p * Ks[kk][cc];
            a1 += p * Ks[kk][cc + 32];
        }
        __syncthreads();
    }
    outb[base + (size_t)(q0 + rr) * D_ + cc]      = f2bf(a0 * inv);
    outb[base + (size_t)(q0 + rr) * D_ + cc + 32] = f2bf(a1 * inv);
}

extern "C" void kernel_launch(void* const* d_in, const int* in_sizes, int n_in,
                              void* d_out, int out_size, void* d_ws, size_t ws_size,
                              hipStream_t stream)
{
    const float* x    = (const float*)d_in[0];
    const void*  adj  = d_in[1];
    const float* ea   = (const float*)d_in[2];
    const int*   ei   = (const int*)d_in[3];
    const float* g1   = (const float*)d_in[4];
    const float* bn1  = (const float*)d_in[5];
    const float* Wq   = (const float*)d_in[6];
    const float* bq   = (const float*)d_in[7];
    const float* Wk   = (const float*)d_in[8];
    const float* bk   = (const float*)d_in[9];
    const float* Wv   = (const float*)d_in[10];
    const float* bv   = (const float*)d_in[11];
    const float* Wo   = (const float*)d_in[12];
    const float* bo   = (const float*)d_in[13];
    const float* g2   = (const float*)d_in[14];
    const float* bn2  = (const float*)d_in[15];
    const float* W1   = (const float*)d_in[16];
    const float* mb1  = (const float*)d_in[17];
    const float* W2   = (const float*)d_in[18];
    const float* mb2  = (const float*)d_in[19];
    const float* epW1 = (const float*)d_in[20];
    const float* epb1 = (const float*)d_in[21];
    const float* epW2 = (const float*)d_in[22];
    const float* epb2 = (const float*)d_in[23];

    char* ws = (char*)d_ws;
    size_t off = 0;
    auto carve = [&](size_t bytes) -> void* {
        void* p = ws + off;
        off += (bytes + 255) & ~(size_t)255;
        return p;
    };
    unsigned short* wqt  = (unsigned short*)carve((size_t)D_ * D_ * 2);
    unsigned short* wkt  = (unsigned short*)carve((size_t)D_ * D_ * 2);
    unsigned short* wvt  = (unsigned short*)carve((size_t)D_ * D_ * 2);
    unsigned short* wot  = (unsigned short*)carve((size_t)D_ * D_ * 2);
    unsigned short* w1t  = (unsigned short*)carve((size_t)FF_ * D_ * 2);  // [3072][768]
    unsigned short* w2t  = (unsigned short*)carve((size_t)D_ * FF_ * 2);  // [768][3072]
    float*          proj = (float*)carve((size_t)E_ * H_ * 4);
    int*            winner = (int*)carve((size_t)S_ * S_ * 4);
    int*            flag = (int*)carve(256);
    unsigned short* nxb  = (unsigned short*)carve((size_t)B_ * S_ * D_ * 2);  // reused as ln2b
    unsigned short* attnb= (unsigned short*)carve((size_t)B_ * S_ * D_ * 2);
    float*          qf   = (float*)carve((size_t)B_ * S_ * D_ * 4);  // qf+kf reused as hb
    float*          kf   = (float*)carve((size_t)B_ * S_ * D_ * 4);
    float*          vf   = (float*)carve((size_t)B_ * S_ * D_ * 4);  // reused as x2f
    unsigned short* ln2b = nxb;
    unsigned short* hb   = (unsigned short*)qf;   // 2048*3072*2 == 2 * (2048*768*4)
    float*          x2f  = vf;

    const int M = B_ * S_;  // 2048

    hipMemsetAsync(winner, 0xFF, (size_t)S_ * S_ * 4, stream);
    hipMemsetAsync(flag, 0, 4, stream);
    detect_kernel<<<256, 256, 0, stream>>>((const unsigned char*)adj, flag);

    // weight transposes (W[K][N] -> Wt[N][K] bf16)
    wtrans_kernel<<<dim3(D_ / 32, D_ / 32), 256, 0, stream>>>(Wq, wqt, D_, D_);
    wtrans_kernel<<<dim3(D_ / 32, D_ / 32), 256, 0, stream>>>(Wk, wkt, D_, D_);
    wtrans_kernel<<<dim3(D_ / 32, D_ / 32), 256, 0, stream>>>(Wv, wvt, D_, D_);
    wtrans_kernel<<<dim3(D_ / 32, D_ / 32), 256, 0, stream>>>(Wo, wot, D_, D_);
    wtrans_kernel<<<dim3(FF_ / 32, D_ / 32), 256, 0, stream>>>(W1, w1t, D_, FF_);
    wtrans_kernel<<<dim3(D_ / 32, FF_ / 32), 256, 0, stream>>>(W2, w2t, FF_, D_);

    // LN1
    ln_kernel<<<M, 256, 0, stream>>>(x, g1, bn1, nxb);

    // QKV
    gemm_kernel<false, false, false><<<dim3(D_ / 64, M / 64), 256, 0, stream>>>(nxb, wqt, bq, nullptr, qf, M, D_, D_);
    gemm_kernel<false, false, false><<<dim3(D_ / 64, M / 64), 256, 0, stream>>>(nxb, wkt, bk, nullptr, kf, M, D_, D_);
    gemm_kernel<false, false, false><<<dim3(D_ / 64, M / 64), 256, 0, stream>>>(nxb, wvt, bv, nullptr, vf, M, D_, D_);

    // edge bias
    edge_proj_kernel<<<(E_ * H_) / 256, 256, 0, stream>>>(ea, epW1, epb1, epW2, epb2, proj);
    scatter_kernel<<<E_ / 256, 256, 0, stream>>>(ei, winner);

    // attention
    attn_kernel<<<dim3(S_ / 8, H_, B_), 256, 0, stream>>>(qf, kf, vf, adj, flag, winner, proj, attnb);

    // Wo + residual(x) -> x2 (f32, overwrites vf AFTER attention consumed v)
    gemm_kernel<false, true, false><<<dim3(D_ / 64, M / 64), 256, 0, stream>>>(attnb, wot, bo, x, x2f, M, D_, D_);

    // LN2
    ln_kernel<<<M, 256, 0, stream>>>(x2f, g2, bn2, ln2b);

    // MLP
    gemm_kernel<true, false, true><<<dim3(FF_ / 64, M / 64), 256, 0, stream>>>(ln2b, w1t, mb1, nullptr, hb, M, FF_, D_);
    gemm_kernel<false, true, false><<<dim3(D_ / 64, M / 64), 256, 0, stream>>>(hb, w2t, mb2, x2f, d_out, M, D_, FF_);
}

// Round 2
// 364.019 us; speedup vs baseline: 2.5358x; 2.5358x over previous
//
#include <hip/hip_runtime.h>
#include <hip/hip_bf16.h>

#define B_ 2
#define S_ 1024
#define D_ 768
#define H_ 12
#define HD_ 64
#define FF_ 3072
#define E_ 32768

typedef short bf16x8 __attribute__((ext_vector_type(8)));
typedef float f32x4 __attribute__((ext_vector_type(4)));

__device__ __forceinline__ unsigned short f2bf(float f) {
    __hip_bfloat16 h = __float2bfloat16(f);
    return __builtin_bit_cast(unsigned short, h);
}
__device__ __forceinline__ float gelu_exact(float x) {
    return 0.5f * x * (1.0f + erff(x * 0.70710678118654752f));
}

// ---------------- LayerNorm: f32 in -> bf16 out (row = 768) ----------------
__global__ __launch_bounds__(256) void ln_kernel(
    const float* __restrict__ x, const float* __restrict__ g,
    const float* __restrict__ b, unsigned short* __restrict__ out)
{
    const int row = blockIdx.x;
    const int t = threadIdx.x;
    const float* xr = x + (size_t)row * D_;
    float v0 = xr[t], v1 = xr[t + 256], v2 = xr[t + 512];
    float s = v0 + v1 + v2, s2 = v0 * v0 + v1 * v1 + v2 * v2;
    for (int m = 32; m; m >>= 1) { s += __shfl_xor(s, m); s2 += __shfl_xor(s2, m); }
    __shared__ float red[8];
    const int w = t >> 6;
    if ((t & 63) == 0) { red[w] = s; red[4 + w] = s2; }
    __syncthreads();
    s = red[0] + red[1] + red[2] + red[3];
    s2 = red[4] + red[5] + red[6] + red[7];
    const float mean = s * (1.f / D_);
    const float var = s2 * (1.f / D_) - mean * mean;
    const float rstd = rsqrtf(var + 1e-5f);
    unsigned short* orow = out + (size_t)row * D_;
    orow[t]       = f2bf((v0 - mean) * rstd * g[t]       + b[t]);
    orow[t + 256] = f2bf((v1 - mean) * rstd * g[t + 256] + b[t + 256]);
    orow[t + 512] = f2bf((v2 - mean) * rstd * g[t + 512] + b[t + 512]);
}

// ------------- weight transpose+convert: W[K][N] f32 -> Wt[N][K] bf16 -------------
__global__ __launch_bounds__(256) void wtrans_kernel(
    const float* __restrict__ W, unsigned short* __restrict__ Wt, int K, int N)
{
    __shared__ float tile[32][33];
    const int tx = threadIdx.x & 31, ty = threadIdx.x >> 5;  // ty 0..7
    const int nb = blockIdx.x * 32, kb = blockIdx.y * 32;
    for (int r = 0; r < 32; r += 8)
        tile[ty + r][tx] = W[(size_t)(kb + ty + r) * N + nb + tx];
    __syncthreads();
    for (int r = 0; r < 32; r += 8)
        Wt[(size_t)(nb + ty + r) * K + kb + tx] = f2bf(tile[tx][ty + r]);
}

// ---------------- bf16 MFMA GEMM: C[M][N] = (A[M][K] @ Bt[N][K]^T + bias)*oscale ----------------
// 64x64 tile, BK=32, 4 waves (2x2), each wave 32x32 via 2x2 MFMA 16x16x32.
template<bool GELU, bool RES, bool OUTBF>
__global__ __launch_bounds__(256) void gemm_kernel(
    const unsigned short* __restrict__ A, const unsigned short* __restrict__ Bt,
    const float* __restrict__ bias, const float* __restrict__ res,
    void* __restrict__ outp, int M, int N, int K, float oscale)
{
    __shared__ unsigned short As[64][40];  // +8 pad: 20-dword stride -> 2-way (free)
    __shared__ unsigned short Bs[64][40];
    const int m0 = blockIdx.y * 64, n0 = blockIdx.x * 64;
    const int t = threadIdx.x;
    const int w = t >> 6, l = t & 63;
    const int wm = w >> 1, wn = w & 1;
    const int r = l & 15, g = l >> 4;
    const int srow = t >> 2, sseg = t & 3;
    f32x4 acc[2][2] = {};
    for (int k0 = 0; k0 < K; k0 += 32) {
        __syncthreads();
        const uint4 av = *reinterpret_cast<const uint4*>(A + (size_t)(m0 + srow) * K + k0 + sseg * 8);
        *reinterpret_cast<uint4*>(&As[srow][sseg * 8]) = av;
        const uint4 bv = *reinterpret_cast<const uint4*>(Bt + (size_t)(n0 + srow) * K + k0 + sseg * 8);
        *reinterpret_cast<uint4*>(&Bs[srow][sseg * 8]) = bv;
        __syncthreads();
        bf16x8 af[2], bfr[2];
        af[0]  = *reinterpret_cast<const bf16x8*>(&As[wm * 32 + r][g * 8]);
        af[1]  = *reinterpret_cast<const bf16x8*>(&As[wm * 32 + 16 + r][g * 8]);
        bfr[0] = *reinterpret_cast<const bf16x8*>(&Bs[wn * 32 + r][g * 8]);
        bfr[1] = *reinterpret_cast<const bf16x8*>(&Bs[wn * 32 + 16 + r][g * 8]);
        for (int m = 0; m < 2; m++)
            for (int n = 0; n < 2; n++)
                acc[m][n] = __builtin_amdgcn_mfma_f32_16x16x32_bf16(af[m], bfr[n], acc[m][n], 0, 0, 0);
    }
    for (int m = 0; m < 2; m++)
        for (int n = 0; n < 2; n++) {
            const int col = n0 + wn * 32 + n * 16 + r;
            const float bvv = bias[col];
            for (int j = 0; j < 4; j++) {
                const int row = m0 + wm * 32 + m * 16 + g * 4 + j;
                float v = (acc[m][n][j] + bvv) * oscale;
                if (RES) v += res[(size_t)row * N + col];
                if (GELU) v = gelu_exact(v);
                if (OUTBF) ((unsigned short*)outp)[(size_t)row * N + col] = f2bf(v);
                else       ((float*)outp)[(size_t)row * N + col] = v;
            }
        }
}

// ---------------- V transpose: vb[b][s][h*64+d] bf16 -> vt[b][h][d][s] bf16 ----------------
__global__ __launch_bounds__(256) void vtrans_kernel(
    const unsigned short* __restrict__ vb, unsigned short* __restrict__ vt)
{
    __shared__ unsigned short T[64][68];
    const int t = threadIdx.x;
    const int s0 = blockIdx.x * 64;
    const int h = blockIdx.y, b = blockIdx.z;
    const int r = t >> 2, seg = t & 3;
    const unsigned short* src = vb + ((size_t)(b * S_ + s0 + r)) * D_ + h * HD_ + seg * 16;
    *reinterpret_cast<uint4*>(&T[r][seg * 16])     = *reinterpret_cast<const uint4*>(src);
    *reinterpret_cast<uint4*>(&T[r][seg * 16 + 8]) = *reinterpret_cast<const uint4*>(src + 8);
    __syncthreads();
    unsigned short tmp[16];
    for (int i = 0; i < 16; i++) tmp[i] = T[seg * 16 + i][r];
    unsigned short* dst = vt + ((size_t)(b * H_ + h) * HD_ + r) * S_ + s0 + seg * 16;
    *reinterpret_cast<uint4*>(dst)     = *reinterpret_cast<uint4*>(&tmp[0]);
    *reinterpret_cast<uint4*>(dst + 8) = *reinterpret_cast<uint4*>(&tmp[8]);
}

// ---------------- edge-attr per-head MLP: proj[e][h] ----------------
__global__ __launch_bounds__(256) void edge_proj_kernel(
    const float* __restrict__ ea, const float* __restrict__ W1, const float* __restrict__ b1,
    const float* __restrict__ W2, const float* __restrict__ b2, float* __restrict__ proj)
{
    const int tid = blockIdx.x * 256 + threadIdx.x;  // E_*H_ = 393216
    const int e = tid / H_, h = tid - e * H_;
    const float a = ea[e];
    float s = 0.f;
    for (int j = 0; j < 16; j++) {
        const float tv = a * W1[h * 16 + j] + b1[h * 16 + j];
        s += gelu_exact(tv) * W2[h * 16 + j];
    }
    proj[tid] = s + b2[h];
}

// last-write-wins scatter: winner[src*S+dst] = max edge idx
__global__ __launch_bounds__(256) void scatter_kernel(const int* __restrict__ ei, int* __restrict__ winner)
{
    const int e = blockIdx.x * 256 + threadIdx.x;  // 32768
    const int s = ei[e], d = ei[E_ + e];
    atomicMax(&winner[s * S_ + d], e);
}

// detect adj_mask storage: uint8 (flag=1) vs int32 (flag=0)
__global__ __launch_bounds__(256) void detect_kernel(const unsigned char* __restrict__ m, int* __restrict__ flag)
{
    const int i = blockIdx.x * 256 + threadIdx.x;  // 65536 probes, bytes at 4i+1 (safe both layouts)
    const unsigned char bval = m[i * 4 + 1];
    unsigned long long bl = __ballot(bval != 0);
    if ((threadIdx.x & 63) == 0 && bl) atomicOr(flag, 1);
}

// ---------------- MFMA flash attention: block = (b, h, 64 q-rows), 4 waves x 16 rows ----------------
#define KP 72  // padded LDS row (bf16 elems)
__global__ __launch_bounds__(256) void attn_mfma_kernel(
    const unsigned short* __restrict__ qb, const unsigned short* __restrict__ kb,
    const unsigned short* __restrict__ vt,
    const void* __restrict__ adj, const int* __restrict__ fmtflag,
    const int* __restrict__ winner, const float* __restrict__ proj,
    unsigned short* __restrict__ outb)
{
    __shared__ unsigned short Ks[64][KP];      // K rows [k_local][d]
    __shared__ unsigned short Vs[64][KP];      // V^T rows [d][k_local]
    __shared__ unsigned short Ps[4][16][KP];   // per-wave P tile [qrow][k_local]
    const int t = threadIdx.x;
    const int w = t >> 6, l = t & 63;
    const int lr = l & 15, g = l >> 4;
    const int q0 = blockIdx.x * 64;
    const int h = blockIdx.y, b = blockIdx.z;
    const size_t qkbase = ((size_t)b * S_) * D_ + h * HD_;
    const size_t vtbase = (size_t)(b * H_ + h) * HD_ * S_;
    const int fmt = *fmtflag;
    const unsigned char* mu8 = (const unsigned char*)adj + (size_t)b * S_ * S_;
    const int* mi32 = (const int*)adj + (size_t)b * S_ * S_;

    // Q A-fragments (row = lr within wave's 16 rows)
    const int qrow = q0 + w * 16 + lr;
    const bf16x8 af0 = *reinterpret_cast<const bf16x8*>(qb + qkbase + (size_t)qrow * D_ + g * 8);
    const bf16x8 af1 = *reinterpret_cast<const bf16x8*>(qb + qkbase + (size_t)qrow * D_ + 32 + g * 8);

    float m_run[4], l_run[4];
    f32x4 acc[4] = {};
    for (int j = 0; j < 4; j++) { m_run[j] = -3.0e38f; l_run[j] = 0.f; }

    for (int kt = 0; kt < S_; kt += 64) {
        __syncthreads();
        {   // stage K tile and V^T tile
            const int kk = t >> 2, seg = t & 3;
            const unsigned short* ksrc = kb + qkbase + (size_t)(kt + kk) * D_ + seg * 16;
            *reinterpret_cast<uint4*>(&Ks[kk][seg * 16])     = *reinterpret_cast<const uint4*>(ksrc);
            *reinterpret_cast<uint4*>(&Ks[kk][seg * 16 + 8]) = *reinterpret_cast<const uint4*>(ksrc + 8);
            const unsigned short* vsrc = vt + vtbase + (size_t)kk * S_ + kt + seg * 16;
            *reinterpret_cast<uint4*>(&Vs[kk][seg * 16])     = *reinterpret_cast<const uint4*>(vsrc);
            *reinterpret_cast<uint4*>(&Vs[kk][seg * 16 + 8]) = *reinterpret_cast<const uint4*>(vsrc + 8);
        }
        __syncthreads();
        // ---- QK^T: 4 col-tiles of 16 ----
        f32x4 sc[4];
        for (int n = 0; n < 4; n++) {
            const bf16x8 b0 = *reinterpret_cast<const bf16x8*>(&Ks[n * 16 + lr][g * 8]);
            const bf16x8 b1 = *reinterpret_cast<const bf16x8*>(&Ks[n * 16 + lr][32 + g * 8]);
            f32x4 z = {};
            z = __builtin_amdgcn_mfma_f32_16x16x32_bf16(af0, b0, z, 0, 0, 0);
            z = __builtin_amdgcn_mfma_f32_16x16x32_bf16(af1, b1, z, 0, 0, 0);
            sc[n] = z;
        }
        // ---- mask + edge bias on C fragments (col=lr, row=g*4+j) ----
        float tmax[4] = {-3.0e38f, -3.0e38f, -3.0e38f, -3.0e38f};
        for (int n = 0; n < 4; n++) {
            const int kg = kt + n * 16 + lr;
            for (int j = 0; j < 4; j++) {
                const int qg = q0 + w * 16 + g * 4 + j;
                const bool msk = fmt ? (mu8[(size_t)qg * S_ + kg] != 0)
                                     : (mi32[(size_t)qg * S_ + kg] != 0);
                float sval;
                if (msk) {
                    const int e = winner[qg * S_ + kg];
                    sval = sc[n][j] + ((e >= 0) ? proj[(size_t)e * H_ + h] : 0.f);
                } else sval = -1e9f;
                sc[n][j] = sval;
                tmax[j] = fmaxf(tmax[j], sval);
            }
        }
        // ---- online softmax (row reduce across the 16 col-lanes) ----
        float pscale[4];
        for (int j = 0; j < 4; j++) {
            float tm = tmax[j];
            tm = fmaxf(tm, __shfl_xor(tm, 1));
            tm = fmaxf(tm, __shfl_xor(tm, 2));
            tm = fmaxf(tm, __shfl_xor(tm, 4));
            tm = fmaxf(tm, __shfl_xor(tm, 8));
            const float mnew = fmaxf(m_run[j], tm);
            pscale[j] = __expf(m_run[j] - mnew);
            m_run[j] = mnew;
            l_run[j] *= pscale[j];
        }
        float psum[4] = {0.f, 0.f, 0.f, 0.f};
        for (int n = 0; n < 4; n++) {
            for (int j = 0; j < 4; j++) {
                const float p = __expf(sc[n][j] - m_run[j]);
                psum[j] += p;
                Ps[w][g * 4 + j][n * 16 + lr] = f2bf(p);
            }
        }
        for (int j = 0; j < 4; j++) {
            float s = psum[j];
            s += __shfl_xor(s, 1); s += __shfl_xor(s, 2);
            s += __shfl_xor(s, 4); s += __shfl_xor(s, 8);
            l_run[j] += s;
            for (int n2 = 0; n2 < 4; n2++) acc[n2][j] *= pscale[j];
        }
        // ---- PV (P from per-wave LDS, V^T fragments) ----
        const bf16x8 pa0 = *reinterpret_cast<const bf16x8*>(&Ps[w][lr][g * 8]);
        const bf16x8 pa1 = *reinterpret_cast<const bf16x8*>(&Ps[w][lr][32 + g * 8]);
        for (int n2 = 0; n2 < 4; n2++) {
            const bf16x8 vb0 = *reinterpret_cast<const bf16x8*>(&Vs[n2 * 16 + lr][g * 8]);
            const bf16x8 vb1 = *reinterpret_cast<const bf16x8*>(&Vs[n2 * 16 + lr][32 + g * 8]);
            acc[n2] = __builtin_amdgcn_mfma_f32_16x16x32_bf16(pa0, vb0, acc[n2], 0, 0, 0);
            acc[n2] = __builtin_amdgcn_mfma_f32_16x16x32_bf16(pa1, vb1, acc[n2], 0, 0, 0);
        }
    }
    // ---- epilogue ----
    for (int n2 = 0; n2 < 4; n2++) {
        const int d = n2 * 16 + lr;
        for (int j = 0; j < 4; j++) {
            const int qg = q0 + w * 16 + g * 4 + j;
            outb[qkbase + (size_t)qg * D_ + d] = f2bf(acc[n2][j] / l_run[j]);
        }
    }
}

extern "C" void kernel_launch(void* const* d_in, const int* in_sizes, int n_in,
                              void* d_out, int out_size, void* d_ws, size_t ws_size,
                              hipStream_t stream)
{
    const float* x    = (const float*)d_in[0];
    const void*  adj  = d_in[1];
    const float* ea   = (const float*)d_in[2];
    const int*   ei   = (const int*)d_in[3];
    const float* g1   = (const float*)d_in[4];
    const float* bn1  = (const float*)d_in[5];
    const float* Wq   = (const float*)d_in[6];
    const float* bq   = (const float*)d_in[7];
    const float* Wk   = (const float*)d_in[8];
    const float* bk   = (const float*)d_in[9];
    const float* Wv   = (const float*)d_in[10];
    const float* bv   = (const float*)d_in[11];
    const float* Wo   = (const float*)d_in[12];
    const float* bo   = (const float*)d_in[13];
    const float* g2   = (const float*)d_in[14];
    const float* bn2  = (const float*)d_in[15];
    const float* W1   = (const float*)d_in[16];
    const float* mb1  = (const float*)d_in[17];
    const float* W2   = (const float*)d_in[18];
    const float* mb2  = (const float*)d_in[19];
    const float* epW1 = (const float*)d_in[20];
    const float* epb1 = (const float*)d_in[21];
    const float* epW2 = (const float*)d_in[22];
    const float* epb2 = (const float*)d_in[23];

    char* ws = (char*)d_ws;
    size_t off = 0;
    auto carve = [&](size_t bytes) -> void* {
        void* p = ws + off;
        off += (bytes + 255) & ~(size_t)255;
        return p;
    };
    unsigned short* wqt  = (unsigned short*)carve((size_t)D_ * D_ * 2);
    unsigned short* wkt  = (unsigned short*)carve((size_t)D_ * D_ * 2);
    unsigned short* wvt  = (unsigned short*)carve((size_t)D_ * D_ * 2);
    unsigned short* wot  = (unsigned short*)carve((size_t)D_ * D_ * 2);
    unsigned short* w1t  = (unsigned short*)carve((size_t)FF_ * D_ * 2);  // [3072][768]
    unsigned short* w2t  = (unsigned short*)carve((size_t)D_ * FF_ * 2);  // [768][3072]
    float*          proj = (float*)carve((size_t)E_ * H_ * 4);
    int*            winner = (int*)carve((size_t)S_ * S_ * 4);
    int*            flag = (int*)carve(256);
    unsigned short* nxb  = (unsigned short*)carve((size_t)B_ * S_ * D_ * 2);  // reused as ln2b
    unsigned short* attnb= (unsigned short*)carve((size_t)B_ * S_ * D_ * 2);
    unsigned short* qbuf = (unsigned short*)carve((size_t)B_ * S_ * D_ * 2);  // qbuf..vtb reused as hb
    unsigned short* kbuf = (unsigned short*)carve((size_t)B_ * S_ * D_ * 2);
    unsigned short* vbuf = (unsigned short*)carve((size_t)B_ * S_ * D_ * 2);
    unsigned short* vtb  = (unsigned short*)carve((size_t)B_ * S_ * D_ * 2);
    float*          x2f  = (float*)carve((size_t)B_ * S_ * D_ * 4);
    unsigned short* ln2b = nxb;
    unsigned short* hb   = qbuf;  // 12 MB = 4 x 3 MB (qbuf,kbuf,vbuf,vtb), free after attention

    const int M = B_ * S_;  // 2048

    hipMemsetAsync(winner, 0xFF, (size_t)S_ * S_ * 4, stream);
    hipMemsetAsync(flag, 0, 4, stream);
    detect_kernel<<<256, 256, 0, stream>>>((const unsigned char*)adj, flag);

    // weight transposes (W[K][N] -> Wt[N][K] bf16)
    wtrans_kernel<<<dim3(D_ / 32, D_ / 32), 256, 0, stream>>>(Wq, wqt, D_, D_);
    wtrans_kernel<<<dim3(D_ / 32, D_ / 32), 256, 0, stream>>>(Wk, wkt, D_, D_);
    wtrans_kernel<<<dim3(D_ / 32, D_ / 32), 256, 0, stream>>>(Wv, wvt, D_, D_);
    wtrans_kernel<<<dim3(D_ / 32, D_ / 32), 256, 0, stream>>>(Wo, wot, D_, D_);
    wtrans_kernel<<<dim3(FF_ / 32, D_ / 32), 256, 0, stream>>>(W1, w1t, D_, FF_);
    wtrans_kernel<<<dim3(D_ / 32, FF_ / 32), 256, 0, stream>>>(W2, w2t, FF_, D_);

    // LN1
    ln_kernel<<<M, 256, 0, stream>>>(x, g1, bn1, nxb);

    // QKV (bf16 out; Q pre-scaled by 1/sqrt(hd)=0.125)
    gemm_kernel<false, false, true><<<dim3(D_ / 64, M / 64), 256, 0, stream>>>(nxb, wqt, bq, nullptr, qbuf, M, D_, D_, 0.125f);
    gemm_kernel<false, false, true><<<dim3(D_ / 64, M / 64), 256, 0, stream>>>(nxb, wkt, bk, nullptr, kbuf, M, D_, D_, 1.0f);
    gemm_kernel<false, false, true><<<dim3(D_ / 64, M / 64), 256, 0, stream>>>(nxb, wvt, bv, nullptr, vbuf, M, D_, D_, 1.0f);

    // V transpose to [b][h][d][s]
    vtrans_kernel<<<dim3(S_ / 64, H_, B_), 256, 0, stream>>>(vbuf, vtb);

    // edge bias
    edge_proj_kernel<<<(E_ * H_) / 256, 256, 0, stream>>>(ea, epW1, epb1, epW2, epb2, proj);
    scatter_kernel<<<E_ / 256, 256, 0, stream>>>(ei, winner);

    // attention (MFMA flash)
    attn_mfma_kernel<<<dim3(S_ / 64, H_, B_), 256, 0, stream>>>(qbuf, kbuf, vtb, adj, flag, winner, proj, attnb);

    // Wo + residual(x) -> x2 (f32)
    gemm_kernel<false, true, false><<<dim3(D_ / 64, M / 64), 256, 0, stream>>>(attnb, wot, bo, x, x2f, M, D_, D_, 1.0f);

    // LN2
    ln_kernel<<<M, 256, 0, stream>>>(x2f, g2, bn2, ln2b);

    // MLP
    gemm_kernel<true, false, true><<<dim3(FF_ / 64, M / 64), 256, 0, stream>>>(ln2b, w1t, mb1, nullptr, hb, M, FF_, D_, 1.0f);
    gemm_kernel<false, true, false><<<dim3(D_ / 64, M / 64), 256, 0, stream>>>(hb, w2t, mb2, x2f, d_out, M, D_, FF_, 1.0f);
}

// Round 3
// 246.331 us; speedup vs baseline: 3.7473x; 1.4778x over previous
//
#include <hip/hip_runtime.h>
#include <hip/hip_bf16.h>

#define B_ 2
#define S_ 1024
#define D_ 768
#define H_ 12
#define HD_ 64
#define FF_ 3072
#define E_ 32768
#define QS_ 2304   // fused QKV row stride

typedef short bf16x8 __attribute__((ext_vector_type(8)));
typedef float f32x4 __attribute__((ext_vector_type(4)));

// XOR swizzle: 8-elem seg s of row r lives at elem offset SW(r,s)
#define SW(row, seg) ((((seg) ^ ((row) & 7)) * 8))

__device__ __forceinline__ unsigned short f2bf(float f) {
    __hip_bfloat16 h = __float2bfloat16(f);
    return __builtin_bit_cast(unsigned short, h);
}
__device__ __forceinline__ float bf2f(unsigned short u) {
    unsigned int v = ((unsigned int)u) << 16;
    return __builtin_bit_cast(float, v);
}
__device__ __forceinline__ float gelu_exact(float x) {
    return 0.5f * x * (1.0f + erff(x * 0.70710678118654752f));
}

// ---------------- LayerNorm: f32 in -> bf16 out (row = 768) ----------------
__global__ __launch_bounds__(256) void ln_kernel(
    const float* __restrict__ x, const float* __restrict__ g,
    const float* __restrict__ b, unsigned short* __restrict__ out)
{
    const int row = blockIdx.x;
    const int t = threadIdx.x;
    const float* xr = x + (size_t)row * D_;
    float v0 = xr[t], v1 = xr[t + 256], v2 = xr[t + 512];
    float s = v0 + v1 + v2, s2 = v0 * v0 + v1 * v1 + v2 * v2;
    for (int m = 32; m; m >>= 1) { s += __shfl_xor(s, m); s2 += __shfl_xor(s2, m); }
    __shared__ float red[8];
    const int w = t >> 6;
    if ((t & 63) == 0) { red[w] = s; red[4 + w] = s2; }
    __syncthreads();
    s = red[0] + red[1] + red[2] + red[3];
    s2 = red[4] + red[5] + red[6] + red[7];
    const float mean = s * (1.f / D_);
    const float var = s2 * (1.f / D_) - mean * mean;
    const float rstd = rsqrtf(var + 1e-5f);
    unsigned short* orow = out + (size_t)row * D_;
    orow[t]       = f2bf((v0 - mean) * rstd * g[t]       + b[t]);
    orow[t + 256] = f2bf((v1 - mean) * rstd * g[t + 256] + b[t + 256]);
    orow[t + 512] = f2bf((v2 - mean) * rstd * g[t + 512] + b[t + 512]);
}

// ------------- weight transpose+convert: W[K][N] f32 -> Wt[N][K] bf16 -------------
__global__ __launch_bounds__(256) void wtrans_kernel(
    const float* __restrict__ W, unsigned short* __restrict__ Wt, int K, int N)
{
    __shared__ float tile[32][33];
    const int tx = threadIdx.x & 31, ty = threadIdx.x >> 5;
    const int nb = blockIdx.x * 32, kb = blockIdx.y * 32;
    for (int r = 0; r < 32; r += 8)
        tile[ty + r][tx] = W[(size_t)(kb + ty + r) * N + nb + tx];
    __syncthreads();
    for (int r = 0; r < 32; r += 8)
        Wt[(size_t)(nb + ty + r) * K + kb + tx] = f2bf(tile[tx][ty + r]);
}

// ---------------- 64x64 GEMM (kept for Wo, W2): C = (A @ Bt^T + bias)*osc [+res][gelu] ----------------
template<bool GELU, bool RES, bool OUTBF>
__global__ __launch_bounds__(256) void gemm_kernel(
    const unsigned short* __restrict__ A, const unsigned short* __restrict__ Bt,
    const float* __restrict__ bias, const float* __restrict__ res,
    void* __restrict__ outp, int M, int N, int K, float oscale)
{
    __shared__ unsigned short As[64][40];
    __shared__ unsigned short Bs[64][40];
    const int m0 = blockIdx.y * 64, n0 = blockIdx.x * 64;
    const int t = threadIdx.x;
    const int w = t >> 6, l = t & 63;
    const int wm = w >> 1, wn = w & 1;
    const int r = l & 15, g = l >> 4;
    const int srow = t >> 2, sseg = t & 3;
    f32x4 acc[2][2] = {};
    for (int k0 = 0; k0 < K; k0 += 32) {
        __syncthreads();
        const uint4 av = *reinterpret_cast<const uint4*>(A + (size_t)(m0 + srow) * K + k0 + sseg * 8);
        *reinterpret_cast<uint4*>(&As[srow][sseg * 8]) = av;
        const uint4 bv = *reinterpret_cast<const uint4*>(Bt + (size_t)(n0 + srow) * K + k0 + sseg * 8);
        *reinterpret_cast<uint4*>(&Bs[srow][sseg * 8]) = bv;
        __syncthreads();
        bf16x8 af[2], bfr[2];
        af[0]  = *reinterpret_cast<const bf16x8*>(&As[wm * 32 + r][g * 8]);
        af[1]  = *reinterpret_cast<const bf16x8*>(&As[wm * 32 + 16 + r][g * 8]);
        bfr[0] = *reinterpret_cast<const bf16x8*>(&Bs[wn * 32 + r][g * 8]);
        bfr[1] = *reinterpret_cast<const bf16x8*>(&Bs[wn * 32 + 16 + r][g * 8]);
        for (int m = 0; m < 2; m++)
            for (int n = 0; n < 2; n++)
                acc[m][n] = __builtin_amdgcn_mfma_f32_16x16x32_bf16(af[m], bfr[n], acc[m][n], 0, 0, 0);
    }
    for (int m = 0; m < 2; m++)
        for (int n = 0; n < 2; n++) {
            const int col = n0 + wn * 32 + n * 16 + r;
            const float bvv = bias[col];
            for (int j = 0; j < 4; j++) {
                const int row = m0 + wm * 32 + m * 16 + g * 4 + j;
                float v = (acc[m][n][j] + bvv) * oscale;
                if (RES) v += res[(size_t)row * N + col];
                if (GELU) v = gelu_exact(v);
                if (OUTBF) ((unsigned short*)outp)[(size_t)row * N + col] = f2bf(v);
                else       ((float*)outp)[(size_t)row * N + col] = v;
            }
        }
}

// ---------------- 128x128 GEMM, BK=64, swizzled LDS (QKV fused, W1) ----------------
// scale_below: cols < scale_below get *0.125 (Q prescale in fused QKV)
template<bool GELU, bool OUTBF>
__global__ __launch_bounds__(256) void gemm128_kernel(
    const unsigned short* __restrict__ A, const unsigned short* __restrict__ Bt,
    const float* __restrict__ bias, void* __restrict__ outp,
    int M, int N, int K, int scale_below)
{
    __shared__ unsigned short As[128][64];
    __shared__ unsigned short Bs[128][64];
    const int m0 = blockIdx.y * 128, n0 = blockIdx.x * 128;
    const int t = threadIdx.x;
    const int w = t >> 6, l = t & 63;
    const int wm = w >> 1, wn = w & 1;
    const int lr = l & 15, g = l >> 4;
    f32x4 acc[4][4] = {};
    for (int k0 = 0; k0 < K; k0 += 64) {
        __syncthreads();
        for (int i = 0; i < 4; i++) {
            const int idx = i * 256 + t;         // 0..1023: row 0..127, seg 0..7
            const int row = idx >> 3, seg = idx & 7;
            *reinterpret_cast<uint4*>(&As[row][SW(row, seg)]) =
                *reinterpret_cast<const uint4*>(A + (size_t)(m0 + row) * K + k0 + seg * 8);
            *reinterpret_cast<uint4*>(&Bs[row][SW(row, seg)]) =
                *reinterpret_cast<const uint4*>(Bt + (size_t)(n0 + row) * K + k0 + seg * 8);
        }
        __syncthreads();
        for (int kk = 0; kk < 2; kk++) {
            bf16x8 af[4], bfr[4];
            for (int m = 0; m < 4; m++) {
                const int r = wm * 64 + m * 16 + lr;
                af[m] = *reinterpret_cast<const bf16x8*>(&As[r][SW(r, kk * 4 + g)]);
            }
            for (int n = 0; n < 4; n++) {
                const int r = wn * 64 + n * 16 + lr;
                bfr[n] = *reinterpret_cast<const bf16x8*>(&Bs[r][SW(r, kk * 4 + g)]);
            }
            for (int m = 0; m < 4; m++)
                for (int n = 0; n < 4; n++)
                    acc[m][n] = __builtin_amdgcn_mfma_f32_16x16x32_bf16(af[m], bfr[n], acc[m][n], 0, 0, 0);
        }
    }
    for (int m = 0; m < 4; m++)
        for (int n = 0; n < 4; n++) {
            const int col = n0 + wn * 64 + n * 16 + lr;
            const float scl = (col < scale_below) ? 0.125f : 1.0f;
            const float bvv = bias[col];
            for (int j = 0; j < 4; j++) {
                const int row = m0 + wm * 64 + m * 16 + g * 4 + j;
                float v = (acc[m][n][j] + bvv) * scl;
                if (GELU) v = gelu_exact(v);
                if (OUTBF) ((unsigned short*)outp)[(size_t)row * N + col] = f2bf(v);
                else       ((float*)outp)[(size_t)row * N + col] = v;
            }
        }
}

// ---------------- V transpose: qkv[b][s][2304] (V at col 1536+h*64) -> vt[b][h][d][s] ----------------
__global__ __launch_bounds__(256) void vtrans_kernel(
    const unsigned short* __restrict__ qkv, unsigned short* __restrict__ vt)
{
    __shared__ unsigned short T[64][68];
    const int t = threadIdx.x;
    const int s0 = blockIdx.x * 64;
    const int h = blockIdx.y, b = blockIdx.z;
    const int r = t >> 2, seg = t & 3;
    const unsigned short* src = qkv + (size_t)(b * S_ + s0 + r) * QS_ + 1536 + h * HD_ + seg * 16;
    *reinterpret_cast<uint4*>(&T[r][seg * 16])     = *reinterpret_cast<const uint4*>(src);
    *reinterpret_cast<uint4*>(&T[r][seg * 16 + 8]) = *reinterpret_cast<const uint4*>(src + 8);
    __syncthreads();
    unsigned short tmp[16];
    for (int i = 0; i < 16; i++) tmp[i] = T[seg * 16 + i][r];
    unsigned short* dst = vt + ((size_t)(b * H_ + h) * HD_ + r) * S_ + s0 + seg * 16;
    *reinterpret_cast<uint4*>(dst)     = *reinterpret_cast<uint4*>(&tmp[0]);
    *reinterpret_cast<uint4*>(dst + 8) = *reinterpret_cast<uint4*>(&tmp[8]);
}

// ---------------- edge-attr per-head MLP: proj[e][h] ----------------
__global__ __launch_bounds__(256) void edge_proj_kernel(
    const float* __restrict__ ea, const float* __restrict__ W1, const float* __restrict__ b1,
    const float* __restrict__ W2, const float* __restrict__ b2, float* __restrict__ proj)
{
    const int tid = blockIdx.x * 256 + threadIdx.x;
    const int e = tid / H_, h = tid - e * H_;
    const float a = ea[e];
    float s = 0.f;
    for (int j = 0; j < 16; j++) {
        const float tv = a * W1[h * 16 + j] + b1[h * 16 + j];
        s += gelu_exact(tv) * W2[h * 16 + j];
    }
    proj[tid] = s + b2[h];
}

// last-write-wins scatter: winner[src*S+dst] = max edge idx
__global__ __launch_bounds__(256) void scatter_kernel(const int* __restrict__ ei, int* __restrict__ winner)
{
    const int e = blockIdx.x * 256 + threadIdx.x;
    const int s = ei[e], d = ei[E_ + e];
    atomicMax(&winner[s * S_ + d], e);
}

// detect adj_mask storage: uint8 (flag=1) vs int32 (flag=0)
__global__ __launch_bounds__(256) void detect_kernel(const unsigned char* __restrict__ m, int* __restrict__ flag)
{
    const int i = blockIdx.x * 256 + threadIdx.x;
    const unsigned char bval = m[i * 4 + 1];
    unsigned long long bl = __ballot(bval != 0);
    if ((threadIdx.x & 63) == 0 && bl) atomicOr(flag, 1);
}

// ---------------- ebias[h][q][k] bf16 = winner>=0 ? proj[winner][h] : 0 ----------------
__global__ __launch_bounds__(256) void ebias_kernel(
    const int* __restrict__ winner, const float* __restrict__ proj,
    unsigned short* __restrict__ ebias)
{
    const int q = blockIdx.x;
    const int t = threadIdx.x;
    for (int i = 0; i < 4; i++) {
        const int k = i * 256 + t;
        const int e = winner[q * S_ + k];
        if (e >= 0) {
            for (int h = 0; h < H_; h++)
                ebias[((size_t)h * S_ + q) * S_ + k] = f2bf(proj[(size_t)e * H_ + h]);
        } else {
            for (int h = 0; h < H_; h++)
                ebias[((size_t)h * S_ + q) * S_ + k] = 0;
        }
    }
}

// ---------------- mask bit-pack: mp[b][q][32] u32 ----------------
__global__ __launch_bounds__(256) void maskpack_kernel(
    const void* __restrict__ adj, const int* __restrict__ fmtflag, unsigned int* __restrict__ mp)
{
    __shared__ unsigned int words[32];
    const int q = blockIdx.x, b = blockIdx.y;
    const int t = threadIdx.x;
    if (t < 32) words[t] = 0;
    __syncthreads();
    const int fmt = *fmtflag;
    const unsigned char* mu8 = (const unsigned char*)adj;
    const int* mi32 = (const int*)adj;
    const size_t mbase = ((size_t)b * S_ + q) * S_;
    for (int i = 0; i < 4; i++) {
        const int k = i * 256 + t;
        const bool msk = fmt ? (mu8[mbase + k] != 0) : (mi32[mbase + k] != 0);
        if (msk) atomicOr(&words[k >> 5], 1u << (k & 31));
    }
    __syncthreads();
    if (t < 32) mp[((size_t)b * S_ + q) * 32 + t] = words[t];
}

// ---------------- MFMA flash attention: block = (b, h, 64 q-rows), 4 waves x 16 rows ----------------
__global__ __launch_bounds__(256) void attn_mfma_kernel(
    const unsigned short* __restrict__ qkv,   // Q at col 0, K at col 768, stride QS_
    const unsigned short* __restrict__ vt,    // [b][h][d][s]
    const unsigned short* __restrict__ ebias, // [h][q][k]
    const unsigned int* __restrict__ mp,      // [b][q][32]
    unsigned short* __restrict__ outb)        // [b][s][768]
{
    __shared__ unsigned short Ks[64][64];     // swizzled
    __shared__ unsigned short Vs[64][64];     // swizzled (rows = d)
    __shared__ unsigned short Eb[64][72];     // padded, scalar reads
    __shared__ unsigned int   Mw[64][2];
    __shared__ unsigned short Ps[4][16][64];  // swizzled
    const int t = threadIdx.x;
    const int w = t >> 6, l = t & 63;
    const int lr = l & 15, g = l >> 4;
    const int q0 = blockIdx.x * 64;
    const int h = blockIdx.y, b = blockIdx.z;
    const size_t qbase = (size_t)b * S_ * QS_ + h * HD_;        // Q cols
    const size_t kbase = qbase + 768;                            // K cols
    const size_t vtbase = (size_t)(b * H_ + h) * HD_ * S_;
    const size_t obase = (size_t)b * S_ * D_ + h * HD_;

    // Q A-fragments
    const int qrow = q0 + w * 16 + lr;
    const bf16x8 af0 = *reinterpret_cast<const bf16x8*>(qkv + qbase + (size_t)qrow * QS_ + g * 8);
    const bf16x8 af1 = *reinterpret_cast<const bf16x8*>(qkv + qbase + (size_t)qrow * QS_ + 32 + g * 8);

    float m_run[4], l_run[4];
    f32x4 acc[4] = {};
    for (int j = 0; j < 4; j++) { m_run[j] = -3.0e38f; l_run[j] = 0.f; }

    const int srow = t >> 2, sseg = t & 3;
    for (int kt = 0; kt < S_; kt += 64) {
        __syncthreads();
        {   // stage K, V^T (swizzled), ebias tile, mask words
            const unsigned short* ksrc = qkv + kbase + (size_t)(kt + srow) * QS_ + sseg * 16;
            *reinterpret_cast<uint4*>(&Ks[srow][SW(srow, sseg * 2)])     = *reinterpret_cast<const uint4*>(ksrc);
            *reinterpret_cast<uint4*>(&Ks[srow][SW(srow, sseg * 2 + 1)]) = *reinterpret_cast<const uint4*>(ksrc + 8);
            const unsigned short* vsrc = vt + vtbase + (size_t)srow * S_ + kt + sseg * 16;
            *reinterpret_cast<uint4*>(&Vs[srow][SW(srow, sseg * 2)])     = *reinterpret_cast<const uint4*>(vsrc);
            *reinterpret_cast<uint4*>(&Vs[srow][SW(srow, sseg * 2 + 1)]) = *reinterpret_cast<const uint4*>(vsrc + 8);
            const unsigned short* esrc = ebias + ((size_t)h * S_ + q0 + srow) * S_ + kt + sseg * 16;
            *reinterpret_cast<uint4*>(&Eb[srow][sseg * 16])     = *reinterpret_cast<const uint4*>(esrc);
            *reinterpret_cast<uint4*>(&Eb[srow][sseg * 16 + 8]) = *reinterpret_cast<const uint4*>(esrc + 8);
            if (t < 128) Mw[t >> 1][t & 1] = mp[((size_t)b * S_ + q0 + (t >> 1)) * 32 + (kt >> 5) + (t & 1)];
        }
        __syncthreads();
        // ---- QK^T ----
        f32x4 sc[4];
        for (int n = 0; n < 4; n++) {
            const int r = n * 16 + lr;
            const bf16x8 b0 = *reinterpret_cast<const bf16x8*>(&Ks[r][SW(r, g)]);
            const bf16x8 b1 = *reinterpret_cast<const bf16x8*>(&Ks[r][SW(r, 4 + g)]);
            f32x4 z = {};
            z = __builtin_amdgcn_mfma_f32_16x16x32_bf16(af0, b0, z, 0, 0, 0);
            z = __builtin_amdgcn_mfma_f32_16x16x32_bf16(af1, b1, z, 0, 0, 0);
            sc[n] = z;
        }
        // ---- mask + edge bias (C frag: col=lr, row=g*4+j) ----
        float tmax[4] = {-3.0e38f, -3.0e38f, -3.0e38f, -3.0e38f};
        for (int n = 0; n < 4; n++) {
            for (int j = 0; j < 4; j++) {
                const int rq = w * 16 + g * 4 + j;
                const unsigned int word = Mw[rq][n >> 1];
                const bool msk = (word >> ((n & 1) * 16 + lr)) & 1;
                float sval;
                if (msk) sval = sc[n][j] + bf2f(Eb[rq][n * 16 + lr]);
                else sval = -1e9f;
                sc[n][j] = sval;
                tmax[j] = fmaxf(tmax[j], sval);
            }
        }
        // ---- online softmax (reduce across 16 col-lanes) ----
        float pscale[4];
        for (int j = 0; j < 4; j++) {
            float tm = tmax[j];
            tm = fmaxf(tm, __shfl_xor(tm, 1));
            tm = fmaxf(tm, __shfl_xor(tm, 2));
            tm = fmaxf(tm, __shfl_xor(tm, 4));
            tm = fmaxf(tm, __shfl_xor(tm, 8));
            const float mnew = fmaxf(m_run[j], tm);
            pscale[j] = __expf(m_run[j] - mnew);
            m_run[j] = mnew;
            l_run[j] *= pscale[j];
        }
        float psum[4] = {0.f, 0.f, 0.f, 0.f};
        for (int n = 0; n < 4; n++) {
            for (int j = 0; j < 4; j++) {
                const float p = __expf(sc[n][j] - m_run[j]);
                psum[j] += p;
                const int row = g * 4 + j;
                Ps[w][row][SW(row, n * 2 + (lr >> 3)) + (lr & 7)] = f2bf(p);
            }
        }
        for (int j = 0; j < 4; j++) {
            float s = psum[j];
            s += __shfl_xor(s, 1); s += __shfl_xor(s, 2);
            s += __shfl_xor(s, 4); s += __shfl_xor(s, 8);
            l_run[j] += s;
            for (int n2 = 0; n2 < 4; n2++) acc[n2][j] *= pscale[j];
        }
        // ---- PV ----
        const bf16x8 pa0 = *reinterpret_cast<const bf16x8*>(&Ps[w][lr][SW(lr, g)]);
        const bf16x8 pa1 = *reinterpret_cast<const bf16x8*>(&Ps[w][lr][SW(lr, 4 + g)]);
        for (int n2 = 0; n2 < 4; n2++) {
            const int r = n2 * 16 + lr;
            const bf16x8 vb0 = *reinterpret_cast<const bf16x8*>(&Vs[r][SW(r, g)]);
            const bf16x8 vb1 = *reinterpret_cast<const bf16x8*>(&Vs[r][SW(r, 4 + g)]);
            acc[n2] = __builtin_amdgcn_mfma_f32_16x16x32_bf16(pa0, vb0, acc[n2], 0, 0, 0);
            acc[n2] = __builtin_amdgcn_mfma_f32_16x16x32_bf16(pa1, vb1, acc[n2], 0, 0, 0);
        }
    }
    // ---- epilogue ----
    for (int n2 = 0; n2 < 4; n2++) {
        const int d = n2 * 16 + lr;
        for (int j = 0; j < 4; j++) {
            const int qg = q0 + w * 16 + g * 4 + j;
            outb[obase + (size_t)qg * D_ + d] = f2bf(acc[n2][j] / l_run[j]);
        }
    }
}

extern "C" void kernel_launch(void* const* d_in, const int* in_sizes, int n_in,
                              void* d_out, int out_size, void* d_ws, size_t ws_size,
                              hipStream_t stream)
{
    const float* x    = (const float*)d_in[0];
    const void*  adj  = d_in[1];
    const float* ea   = (const float*)d_in[2];
    const int*   ei   = (const int*)d_in[3];
    const float* g1   = (const float*)d_in[4];
    const float* bn1  = (const float*)d_in[5];
    const float* Wq   = (const float*)d_in[6];
    const float* bq   = (const float*)d_in[7];
    const float* Wk   = (const float*)d_in[8];
    const float* bk   = (const float*)d_in[9];
    const float* Wv   = (const float*)d_in[10];
    const float* bv   = (const float*)d_in[11];
    const float* Wo   = (const float*)d_in[12];
    const float* bo   = (const float*)d_in[13];
    const float* g2   = (const float*)d_in[14];
    const float* bn2  = (const float*)d_in[15];
    const float* W1   = (const float*)d_in[16];
    const float* mb1  = (const float*)d_in[17];
    const float* W2   = (const float*)d_in[18];
    const float* mb2  = (const float*)d_in[19];
    const float* epW1 = (const float*)d_in[20];
    const float* epb1 = (const float*)d_in[21];
    const float* epW2 = (const float*)d_in[22];
    const float* epb2 = (const float*)d_in[23];

    char* ws = (char*)d_ws;
    size_t off = 0;
    auto carve = [&](size_t bytes) -> void* {
        void* p = ws + off;
        off += (bytes + 255) & ~(size_t)255;
        return p;
    };
    unsigned short* wqkvt = (unsigned short*)carve((size_t)QS_ * D_ * 2);   // [2304][768]
    unsigned short* wot   = (unsigned short*)carve((size_t)D_ * D_ * 2);
    unsigned short* w1t   = (unsigned short*)carve((size_t)FF_ * D_ * 2);
    unsigned short* w2t   = (unsigned short*)carve((size_t)D_ * FF_ * 2);
    float*          bqkv  = (float*)carve((size_t)QS_ * 4);
    float*          proj  = (float*)carve((size_t)E_ * H_ * 4);
    int*            winner= (int*)carve((size_t)S_ * S_ * 4);
    int*            flag  = (int*)carve(256);
    unsigned short* ebias = (unsigned short*)carve((size_t)H_ * S_ * S_ * 2);  // 25 MB
    unsigned int*   mpk   = (unsigned int*)carve((size_t)B_ * S_ * 32 * 4);
    unsigned short* nxb   = (unsigned short*)carve((size_t)B_ * S_ * D_ * 2);  // reused as ln2b
    unsigned short* attnb = (unsigned short*)carve((size_t)B_ * S_ * D_ * 2);
    unsigned short* qkv   = (unsigned short*)carve((size_t)B_ * S_ * QS_ * 2); // 9.44 MB
    unsigned short* vtb   = (unsigned short*)carve((size_t)B_ * S_ * D_ * 2);  // 3.15 MB (adjacent!)
    float*          x2f   = (float*)carve((size_t)B_ * S_ * D_ * 4);
    unsigned short* ln2b = nxb;
    unsigned short* hb   = qkv;  // [2048][3072] bf16 = 12.58 MB aliases qkv+vtb (dead after attn)

    const int M = B_ * S_;  // 2048

    hipMemsetAsync(winner, 0xFF, (size_t)S_ * S_ * 4, stream);
    hipMemsetAsync(flag, 0, 4, stream);
    detect_kernel<<<256, 256, 0, stream>>>((const unsigned char*)adj, flag);

    // weight transposes
    wtrans_kernel<<<dim3(D_ / 32, D_ / 32), 256, 0, stream>>>(Wq, wqkvt, D_, D_);
    wtrans_kernel<<<dim3(D_ / 32, D_ / 32), 256, 0, stream>>>(Wk, wqkvt + (size_t)768 * D_, D_, D_);
    wtrans_kernel<<<dim3(D_ / 32, D_ / 32), 256, 0, stream>>>(Wv, wqkvt + (size_t)1536 * D_, D_, D_);
    wtrans_kernel<<<dim3(D_ / 32, D_ / 32), 256, 0, stream>>>(Wo, wot, D_, D_);
    wtrans_kernel<<<dim3(FF_ / 32, D_ / 32), 256, 0, stream>>>(W1, w1t, D_, FF_);
    wtrans_kernel<<<dim3(D_ / 32, FF_ / 32), 256, 0, stream>>>(W2, w2t, FF_, D_);

    // fused bias
    hipMemcpyAsync(bqkv,        bq, D_ * 4, hipMemcpyDeviceToDevice, stream);
    hipMemcpyAsync(bqkv + 768,  bk, D_ * 4, hipMemcpyDeviceToDevice, stream);
    hipMemcpyAsync(bqkv + 1536, bv, D_ * 4, hipMemcpyDeviceToDevice, stream);

    // LN1
    ln_kernel<<<M, 256, 0, stream>>>(x, g1, bn1, nxb);

    // fused QKV (bf16 out, Q cols scaled by 0.125)
    gemm128_kernel<false, true><<<dim3(QS_ / 128, M / 128), 256, 0, stream>>>(
        nxb, wqkvt, bqkv, qkv, M, QS_, D_, 768);

    // V transpose
    vtrans_kernel<<<dim3(S_ / 64, H_, B_), 256, 0, stream>>>(qkv, vtb);

    // edge bias pipeline
    edge_proj_kernel<<<(E_ * H_) / 256, 256, 0, stream>>>(ea, epW1, epb1, epW2, epb2, proj);
    scatter_kernel<<<E_ / 256, 256, 0, stream>>>(ei, winner);
    ebias_kernel<<<S_, 256, 0, stream>>>(winner, proj, ebias);
    maskpack_kernel<<<dim3(S_, B_), 256, 0, stream>>>(adj, flag, mpk);

    // attention
    attn_mfma_kernel<<<dim3(S_ / 64, H_, B_), 256, 0, stream>>>(qkv, vtb, ebias, mpk, attnb);

    // Wo + residual(x) -> x2 (f32)
    gemm_kernel<false, true, false><<<dim3(D_ / 64, M / 64), 256, 0, stream>>>(attnb, wot, bo, x, x2f, M, D_, D_, 1.0f);

    // LN2
    ln_kernel<<<M, 256, 0, stream>>>(x2f, g2, bn2, ln2b);

    // MLP
    gemm128_kernel<true, true><<<dim3(FF_ / 128, M / 128), 256, 0, stream>>>(
        ln2b, w1t, mb1, hb, M, FF_, D_, 0);
    gemm_kernel<false, true, false><<<dim3(D_ / 64, M / 64), 256, 0, stream>>>(hb, w2t, mb2, x2f, d_out, M, D_, FF_, 1.0f);
}

// Round 4
// 205.229 us; speedup vs baseline: 4.4978x; 1.2003x over previous
//
#include <hip/hip_runtime.h>
#include <hip/hip_bf16.h>

#define B_ 2
#define S_ 1024
#define D_ 768
#define H_ 12
#define HD_ 64
#define FF_ 3072
#define E_ 32768
#define QS_ 2304   // fused QKV row stride
#define NSPLIT 2   // attention KV splits
#define BHS (B_ * H_ * S_)   // 24576 partial rows per split

typedef short bf16x8 __attribute__((ext_vector_type(8)));
typedef float f32x4 __attribute__((ext_vector_type(4)));

// XOR swizzle: 8-elem seg s of row r lives at elem offset SW(r,s)
#define SW(row, seg) ((((seg) ^ ((row) & 7)) * 8))

__device__ __forceinline__ unsigned short f2bf(float f) {
    __hip_bfloat16 h = __float2bfloat16(f);
    return __builtin_bit_cast(unsigned short, h);
}
__device__ __forceinline__ float bf2f(unsigned short u) {
    unsigned int v = ((unsigned int)u) << 16;
    return __builtin_bit_cast(float, v);
}
__device__ __forceinline__ float gelu_exact(float x) {
    return 0.5f * x * (1.0f + erff(x * 0.70710678118654752f));
}

// ---------------- LayerNorm: f32 in -> bf16 out (row = 768) ----------------
__global__ __launch_bounds__(256) void ln_kernel(
    const float* __restrict__ x, const float* __restrict__ g,
    const float* __restrict__ b, unsigned short* __restrict__ out)
{
    const int row = blockIdx.x;
    const int t = threadIdx.x;
    const float* xr = x + (size_t)row * D_;
    float v0 = xr[t], v1 = xr[t + 256], v2 = xr[t + 512];
    float s = v0 + v1 + v2, s2 = v0 * v0 + v1 * v1 + v2 * v2;
    for (int m = 32; m; m >>= 1) { s += __shfl_xor(s, m); s2 += __shfl_xor(s2, m); }
    __shared__ float red[8];
    const int w = t >> 6;
    if ((t & 63) == 0) { red[w] = s; red[4 + w] = s2; }
    __syncthreads();
    s = red[0] + red[1] + red[2] + red[3];
    s2 = red[4] + red[5] + red[6] + red[7];
    const float mean = s * (1.f / D_);
    const float var = s2 * (1.f / D_) - mean * mean;
    const float rstd = rsqrtf(var + 1e-5f);
    unsigned short* orow = out + (size_t)row * D_;
    orow[t]       = f2bf((v0 - mean) * rstd * g[t]       + b[t]);
    orow[t + 256] = f2bf((v1 - mean) * rstd * g[t + 256] + b[t + 256]);
    orow[t + 512] = f2bf((v2 - mean) * rstd * g[t + 512] + b[t + 512]);
}

// ------------- all weight transposes + bias concat in ONE launch -------------
// z=0..2: Wq/Wk/Wv [768][768] -> wqkvt rows z*768..  (grid x<24, y<24)
// z=3: Wo [768][768] -> wot ; z=4: W1 [768][3072] -> w1t (x=nb<96,y=kb<24)
// z=5: W2 [3072][768] -> w2t (x=kb<96, y=nb<24)
__global__ __launch_bounds__(256) void wtrans_all_kernel(
    const float* __restrict__ Wq, const float* __restrict__ Wk, const float* __restrict__ Wv,
    const float* __restrict__ Wo, const float* __restrict__ W1, const float* __restrict__ W2,
    unsigned short* __restrict__ wqkvt, unsigned short* __restrict__ wot,
    unsigned short* __restrict__ w1t, unsigned short* __restrict__ w2t,
    const float* __restrict__ bq, const float* __restrict__ bk, const float* __restrict__ bv,
    float* __restrict__ bqkv)
{
    const int z = blockIdx.z;
    const float* src; unsigned short* dst; int K, N, nb, kb;
    if (z < 4) {
        if (blockIdx.x >= 24 || blockIdx.y >= 24) return;
        K = 768; N = 768; nb = blockIdx.x * 32; kb = blockIdx.y * 32;
        src = (z == 0) ? Wq : (z == 1) ? Wk : (z == 2) ? Wv : Wo;
        dst = (z == 3) ? wot : wqkvt + (size_t)z * 768 * 768;
    } else if (z == 4) {
        if (blockIdx.y >= 24) return;
        K = 768; N = 3072; nb = blockIdx.x * 32; kb = blockIdx.y * 32;
        src = W1; dst = w1t;
    } else {
        if (blockIdx.y >= 24) return;
        K = 3072; N = 768; nb = blockIdx.y * 32; kb = blockIdx.x * 32;
        src = W2; dst = w2t;
    }
    __shared__ float tile[32][33];
    const int tx = threadIdx.x & 31, ty = threadIdx.x >> 5;
    for (int r = 0; r < 32; r += 8)
        tile[ty + r][tx] = src[(size_t)(kb + ty + r) * N + nb + tx];
    __syncthreads();
    for (int r = 0; r < 32; r += 8)
        dst[(size_t)(nb + ty + r) * K + kb + tx] = f2bf(tile[tx][ty + r]);
    if (z == 0 && blockIdx.x == 0 && blockIdx.y == 0) {
        for (int i = threadIdx.x; i < QS_; i += 256)
            bqkv[i] = (i < 768) ? bq[i] : (i < 1536) ? bk[i - 768] : bv[i - 1536];
    }
}

// ---------------- 64x64 GEMM (Wo): C = (A @ Bt^T + bias) [+res] ----------------
template<bool RES, bool OUTBF>
__global__ __launch_bounds__(256) void gemm_kernel(
    const unsigned short* __restrict__ A, const unsigned short* __restrict__ Bt,
    const float* __restrict__ bias, const float* __restrict__ res,
    void* __restrict__ outp, int M, int N, int K)
{
    __shared__ unsigned short As[64][40];
    __shared__ unsigned short Bs[64][40];
    const int m0 = blockIdx.y * 64, n0 = blockIdx.x * 64;
    const int t = threadIdx.x;
    const int w = t >> 6, l = t & 63;
    const int wm = w >> 1, wn = w & 1;
    const int r = l & 15, g = l >> 4;
    const int srow = t >> 2, sseg = t & 3;
    f32x4 acc[2][2] = {};
    for (int k0 = 0; k0 < K; k0 += 32) {
        __syncthreads();
        const uint4 av = *reinterpret_cast<const uint4*>(A + (size_t)(m0 + srow) * K + k0 + sseg * 8);
        *reinterpret_cast<uint4*>(&As[srow][sseg * 8]) = av;
        const uint4 bv = *reinterpret_cast<const uint4*>(Bt + (size_t)(n0 + srow) * K + k0 + sseg * 8);
        *reinterpret_cast<uint4*>(&Bs[srow][sseg * 8]) = bv;
        __syncthreads();
        bf16x8 af[2], bfr[2];
        af[0]  = *reinterpret_cast<const bf16x8*>(&As[wm * 32 + r][g * 8]);
        af[1]  = *reinterpret_cast<const bf16x8*>(&As[wm * 32 + 16 + r][g * 8]);
        bfr[0] = *reinterpret_cast<const bf16x8*>(&Bs[wn * 32 + r][g * 8]);
        bfr[1] = *reinterpret_cast<const bf16x8*>(&Bs[wn * 32 + 16 + r][g * 8]);
        for (int m = 0; m < 2; m++)
            for (int n = 0; n < 2; n++)
                acc[m][n] = __builtin_amdgcn_mfma_f32_16x16x32_bf16(af[m], bfr[n], acc[m][n], 0, 0, 0);
    }
    for (int m = 0; m < 2; m++)
        for (int n = 0; n < 2; n++) {
            const int col = n0 + wn * 32 + n * 16 + r;
            const float bvv = bias[col];
            for (int j = 0; j < 4; j++) {
                const int row = m0 + wm * 32 + m * 16 + g * 4 + j;
                float v = acc[m][n][j] + bvv;
                if (RES) v += res[(size_t)row * N + col];
                if (OUTBF) ((unsigned short*)outp)[(size_t)row * N + col] = f2bf(v);
                else       ((float*)outp)[(size_t)row * N + col] = v;
            }
        }
}

// ---------------- 64x64 split-K GEMM (W2): partial[z][M][N] f32, no bias ----------------
__global__ __launch_bounds__(256) void gemm_splitk_kernel(
    const unsigned short* __restrict__ A, const unsigned short* __restrict__ Bt,
    float* __restrict__ part, int M, int N, int K, int klen)
{
    __shared__ unsigned short As[64][40];
    __shared__ unsigned short Bs[64][40];
    const int m0 = blockIdx.y * 64, n0 = blockIdx.x * 64;
    const int kbeg = blockIdx.z * klen;
    const int t = threadIdx.x;
    const int w = t >> 6, l = t & 63;
    const int wm = w >> 1, wn = w & 1;
    const int r = l & 15, g = l >> 4;
    const int srow = t >> 2, sseg = t & 3;
    f32x4 acc[2][2] = {};
    for (int k0 = kbeg; k0 < kbeg + klen; k0 += 32) {
        __syncthreads();
        const uint4 av = *reinterpret_cast<const uint4*>(A + (size_t)(m0 + srow) * K + k0 + sseg * 8);
        *reinterpret_cast<uint4*>(&As[srow][sseg * 8]) = av;
        const uint4 bv = *reinterpret_cast<const uint4*>(Bt + (size_t)(n0 + srow) * K + k0 + sseg * 8);
        *reinterpret_cast<uint4*>(&Bs[srow][sseg * 8]) = bv;
        __syncthreads();
        bf16x8 af[2], bfr[2];
        af[0]  = *reinterpret_cast<const bf16x8*>(&As[wm * 32 + r][g * 8]);
        af[1]  = *reinterpret_cast<const bf16x8*>(&As[wm * 32 + 16 + r][g * 8]);
        bfr[0] = *reinterpret_cast<const bf16x8*>(&Bs[wn * 32 + r][g * 8]);
        bfr[1] = *reinterpret_cast<const bf16x8*>(&Bs[wn * 32 + 16 + r][g * 8]);
        for (int m = 0; m < 2; m++)
            for (int n = 0; n < 2; n++)
                acc[m][n] = __builtin_amdgcn_mfma_f32_16x16x32_bf16(af[m], bfr[n], acc[m][n], 0, 0, 0);
    }
    float* op = part + (size_t)blockIdx.z * M * N;
    for (int m = 0; m < 2; m++)
        for (int n = 0; n < 2; n++) {
            const int col = n0 + wn * 32 + n * 16 + r;
            for (int j = 0; j < 4; j++) {
                const int row = m0 + wm * 32 + m * 16 + g * 4 + j;
                op[(size_t)row * N + col] = acc[m][n][j];
            }
        }
}

// ---------------- W2 reduce: d_out = x2 + b2 + p0 + p1 ----------------
__global__ __launch_bounds__(256) void w2_reduce_kernel(
    const float* __restrict__ part, const float* __restrict__ x2,
    const float* __restrict__ b2, float* __restrict__ out)
{
    const int idx = (blockIdx.x * 256 + threadIdx.x) * 4;   // grid 1536 covers 2048*768
    const int col = idx % D_;
    const float4 p0 = *reinterpret_cast<const float4*>(&part[idx]);
    const float4 p1 = *reinterpret_cast<const float4*>(&part[(size_t)B_ * S_ * D_ + idx]);
    const float4 xr = *reinterpret_cast<const float4*>(&x2[idx]);
    const float4 bb = *reinterpret_cast<const float4*>(&b2[col]);
    float4 o;
    o.x = xr.x + bb.x + p0.x + p1.x;
    o.y = xr.y + bb.y + p0.y + p1.y;
    o.z = xr.z + bb.z + p0.z + p1.z;
    o.w = xr.w + bb.w + p0.w + p1.w;
    *reinterpret_cast<float4*>(&out[idx]) = o;
}

// ---------------- 128x128 GEMM, BK=64, swizzled LDS (QKV fused, W1) ----------------
template<bool GELU, bool OUTBF>
__global__ __launch_bounds__(256) void gemm128_kernel(
    const unsigned short* __restrict__ A, const unsigned short* __restrict__ Bt,
    const float* __restrict__ bias, void* __restrict__ outp,
    int M, int N, int K, int scale_below)
{
    __shared__ unsigned short As[128][64];
    __shared__ unsigned short Bs[128][64];
    const int m0 = blockIdx.y * 128, n0 = blockIdx.x * 128;
    const int t = threadIdx.x;
    const int w = t >> 6, l = t & 63;
    const int wm = w >> 1, wn = w & 1;
    const int lr = l & 15, g = l >> 4;
    f32x4 acc[4][4] = {};
    for (int k0 = 0; k0 < K; k0 += 64) {
        __syncthreads();
        for (int i = 0; i < 4; i++) {
            const int idx = i * 256 + t;
            const int row = idx >> 3, seg = idx & 7;
            *reinterpret_cast<uint4*>(&As[row][SW(row, seg)]) =
                *reinterpret_cast<const uint4*>(A + (size_t)(m0 + row) * K + k0 + seg * 8);
            *reinterpret_cast<uint4*>(&Bs[row][SW(row, seg)]) =
                *reinterpret_cast<const uint4*>(Bt + (size_t)(n0 + row) * K + k0 + seg * 8);
        }
        __syncthreads();
        for (int kk = 0; kk < 2; kk++) {
            bf16x8 af[4], bfr[4];
            for (int m = 0; m < 4; m++) {
                const int r = wm * 64 + m * 16 + lr;
                af[m] = *reinterpret_cast<const bf16x8*>(&As[r][SW(r, kk * 4 + g)]);
            }
            for (int n = 0; n < 4; n++) {
                const int r = wn * 64 + n * 16 + lr;
                bfr[n] = *reinterpret_cast<const bf16x8*>(&Bs[r][SW(r, kk * 4 + g)]);
            }
            for (int m = 0; m < 4; m++)
                for (int n = 0; n < 4; n++)
                    acc[m][n] = __builtin_amdgcn_mfma_f32_16x16x32_bf16(af[m], bfr[n], acc[m][n], 0, 0, 0);
        }
    }
    for (int m = 0; m < 4; m++)
        for (int n = 0; n < 4; n++) {
            const int col = n0 + wn * 64 + n * 16 + lr;
            const float scl = (col < scale_below) ? 0.125f : 1.0f;
            const float bvv = bias[col];
            for (int j = 0; j < 4; j++) {
                const int row = m0 + wm * 64 + m * 16 + g * 4 + j;
                float v = (acc[m][n][j] + bvv) * scl;
                if (GELU) v = gelu_exact(v);
                if (OUTBF) ((unsigned short*)outp)[(size_t)row * N + col] = f2bf(v);
                else       ((float*)outp)[(size_t)row * N + col] = v;
            }
        }
}

// ---------------- V transpose: qkv[b][s][2304] (V at col 1536+h*64) -> vt[b][h][d][s] ----------------
__global__ __launch_bounds__(256) void vtrans_kernel(
    const unsigned short* __restrict__ qkv, unsigned short* __restrict__ vt)
{
    __shared__ unsigned short T[64][68];
    const int t = threadIdx.x;
    const int s0 = blockIdx.x * 64;
    const int h = blockIdx.y, b = blockIdx.z;
    const int r = t >> 2, seg = t & 3;
    const unsigned short* src = qkv + (size_t)(b * S_ + s0 + r) * QS_ + 1536 + h * HD_ + seg * 16;
    *reinterpret_cast<uint4*>(&T[r][seg * 16])     = *reinterpret_cast<const uint4*>(src);
    *reinterpret_cast<uint4*>(&T[r][seg * 16 + 8]) = *reinterpret_cast<const uint4*>(src + 8);
    __syncthreads();
    unsigned short tmp[16];
    for (int i = 0; i < 16; i++) tmp[i] = T[seg * 16 + i][r];
    unsigned short* dst = vt + ((size_t)(b * H_ + h) * HD_ + r) * S_ + s0 + seg * 16;
    *reinterpret_cast<uint4*>(dst)     = *reinterpret_cast<uint4*>(&tmp[0]);
    *reinterpret_cast<uint4*>(dst + 8) = *reinterpret_cast<uint4*>(&tmp[8]);
}

// ---------------- edge MLP + scatter fused ----------------
__global__ __launch_bounds__(256) void edge_proj_scatter_kernel(
    const float* __restrict__ ea, const float* __restrict__ W1, const float* __restrict__ b1,
    const float* __restrict__ W2, const float* __restrict__ b2,
    const int* __restrict__ ei, float* __restrict__ proj, int* __restrict__ winner)
{
    const int tid = blockIdx.x * 256 + threadIdx.x;   // E_*H_
    const int e = tid / H_, h = tid - e * H_;
    const float a = ea[e];
    float s = 0.f;
    for (int j = 0; j < 16; j++) {
        const float tv = a * W1[h * 16 + j] + b1[h * 16 + j];
        s += gelu_exact(tv) * W2[h * 16 + j];
    }
    proj[tid] = s + b2[h];
    if (h == 0) {
        const int sn = ei[e], dn = ei[E_ + e];
        atomicMax(&winner[sn * S_ + dn], e);
    }
}

// ---------------- ebias[h][q][k] bf16 (vectorized: 4 k per thread) ----------------
__global__ __launch_bounds__(256) void ebias_kernel(
    const int* __restrict__ winner, const float* __restrict__ proj,
    unsigned short* __restrict__ ebias)
{
    const int q = blockIdx.x;
    const int t = threadIdx.x;
    const int k4 = t * 4;
    const int4 wv = *reinterpret_cast<const int4*>(&winner[q * S_ + k4]);
    for (int h = 0; h < H_; h++) {
        unsigned int lo = 0, hi = 0;
        if (wv.x >= 0) lo |= (unsigned int)f2bf(proj[(size_t)wv.x * H_ + h]);
        if (wv.y >= 0) lo |= ((unsigned int)f2bf(proj[(size_t)wv.y * H_ + h])) << 16;
        if (wv.z >= 0) hi |= (unsigned int)f2bf(proj[(size_t)wv.z * H_ + h]);
        if (wv.w >= 0) hi |= ((unsigned int)f2bf(proj[(size_t)wv.w * H_ + h])) << 16;
        uint2 val; val.x = lo; val.y = hi;
        *reinterpret_cast<uint2*>(&ebias[((size_t)h * S_ + q) * S_ + k4]) = val;
    }
}

// ---------------- mask bit-pack with per-block format self-detect ----------------
__global__ __launch_bounds__(256) void maskpack_kernel(
    const void* __restrict__ adj, unsigned int* __restrict__ mp)
{
    __shared__ unsigned int words[32];
    __shared__ int u8f;
    const int q = blockIdx.x, b = blockIdx.y;
    const int t = threadIdx.x;
    if (t < 32) words[t] = 0;
    if (t == 0) u8f = 0;
    __syncthreads();
    const unsigned int* row8 = (const unsigned int*)((const unsigned char*)adj + ((size_t)b * S_ + q) * S_);
    const unsigned int* row32 = (const unsigned int*)((const int*)adj + ((size_t)b * S_ + q) * S_);
    const unsigned int v = row8[t];
    if (v & 0xFF00FF00u) atomicOr(&u8f, 1);   // odd bytes nonzero => u8 storage (i32 0/1 data has them 0)
    __syncthreads();
    if (u8f) {
        unsigned int nib = 0;
        if (v & 0x000000FFu) nib |= 1u;
        if (v & 0x0000FF00u) nib |= 2u;
        if (v & 0x00FF0000u) nib |= 4u;
        if (v & 0xFF000000u) nib |= 8u;
        if (nib) atomicOr(&words[t >> 3], nib << ((t & 7) * 4));
    } else {
        for (int i = 0; i < 4; i++) {
            const int k = i * 256 + t;
            if (row32[k]) atomicOr(&words[k >> 5], 1u << (k & 31));
        }
    }
    __syncthreads();
    if (t < 32) mp[((size_t)b * S_ + q) * 32 + t] = words[t];
}

// ---------------- MFMA flash attention, KV-split: block = (qt, sp, h, b) ----------------
__global__ __launch_bounds__(256) void attn_mfma_kernel(
    const unsigned short* __restrict__ qkv,   // Q col 0, K col 768, stride QS_
    const unsigned short* __restrict__ vt,    // [b][h][d][s]
    const unsigned short* __restrict__ ebias, // [h][q][k]
    const unsigned int* __restrict__ mp,      // [b][q][32]
    float* __restrict__ pacc,                 // [sp][bh][q][64]
    float2* __restrict__ pml)                 // [sp][bh][q]
{
    __shared__ unsigned short Ks[64][64];
    __shared__ unsigned short Vs[64][64];
    __shared__ unsigned short Eb[64][72];
    __shared__ unsigned int   Mw[64][2];
    __shared__ unsigned short Ps[4][16][64];
    const int t = threadIdx.x;
    const int w = t >> 6, l = t & 63;
    const int lr = l & 15, g = l >> 4;
    const int qt = blockIdx.x & 15, sp = blockIdx.x >> 4;
    const int q0 = qt * 64;
    const int h = blockIdx.y, b = blockIdx.z;
    const int bh = b * H_ + h;
    const size_t qbase = (size_t)b * S_ * QS_ + h * HD_;
    const size_t kbase = qbase + 768;
    const size_t vtbase = (size_t)bh * HD_ * S_;

    const int qrow = q0 + w * 16 + lr;
    const bf16x8 af0 = *reinterpret_cast<const bf16x8*>(qkv + qbase + (size_t)qrow * QS_ + g * 8);
    const bf16x8 af1 = *reinterpret_cast<const bf16x8*>(qkv + qbase + (size_t)qrow * QS_ + 32 + g * 8);

    float m_run[4], l_run[4];
    f32x4 acc[4] = {};
    for (int j = 0; j < 4; j++) { m_run[j] = -3.0e38f; l_run[j] = 0.f; }

    const int srow = t >> 2, sseg = t & 3;
    const int kt_beg = sp * (S_ / NSPLIT), kt_end = kt_beg + S_ / NSPLIT;
    for (int kt = kt_beg; kt < kt_end; kt += 64) {
        __syncthreads();
        {
            const unsigned short* ksrc = qkv + kbase + (size_t)(kt + srow) * QS_ + sseg * 16;
            *reinterpret_cast<uint4*>(&Ks[srow][SW(srow, sseg * 2)])     = *reinterpret_cast<const uint4*>(ksrc);
            *reinterpret_cast<uint4*>(&Ks[srow][SW(srow, sseg * 2 + 1)]) = *reinterpret_cast<const uint4*>(ksrc + 8);
            const unsigned short* vsrc = vt + vtbase + (size_t)srow * S_ + kt + sseg * 16;
            *reinterpret_cast<uint4*>(&Vs[srow][SW(srow, sseg * 2)])     = *reinterpret_cast<const uint4*>(vsrc);
            *reinterpret_cast<uint4*>(&Vs[srow][SW(srow, sseg * 2 + 1)]) = *reinterpret_cast<const uint4*>(vsrc + 8);
            const unsigned short* esrc = ebias + ((size_t)h * S_ + q0 + srow) * S_ + kt + sseg * 16;
            *reinterpret_cast<uint4*>(&Eb[srow][sseg * 16])     = *reinterpret_cast<const uint4*>(esrc);
            *reinterpret_cast<uint4*>(&Eb[srow][sseg * 16 + 8]) = *reinterpret_cast<const uint4*>(esrc + 8);
            if (t < 128) Mw[t >> 1][t & 1] = mp[((size_t)b * S_ + q0 + (t >> 1)) * 32 + (kt >> 5) + (t & 1)];
        }
        __syncthreads();
        f32x4 sc[4];
        for (int n = 0; n < 4; n++) {
            const int r = n * 16 + lr;
            const bf16x8 b0 = *reinterpret_cast<const bf16x8*>(&Ks[r][SW(r, g)]);
            const bf16x8 b1 = *reinterpret_cast<const bf16x8*>(&Ks[r][SW(r, 4 + g)]);
            f32x4 z = {};
            z = __builtin_amdgcn_mfma_f32_16x16x32_bf16(af0, b0, z, 0, 0, 0);
            z = __builtin_amdgcn_mfma_f32_16x16x32_bf16(af1, b1, z, 0, 0, 0);
            sc[n] = z;
        }
        float tmax[4] = {-3.0e38f, -3.0e38f, -3.0e38f, -3.0e38f};
        for (int n = 0; n < 4; n++) {
            for (int j = 0; j < 4; j++) {
                const int rq = w * 16 + g * 4 + j;
                const unsigned int word = Mw[rq][n >> 1];
                const bool msk = (word >> ((n & 1) * 16 + lr)) & 1;
                float sval;
                if (msk) sval = sc[n][j] + bf2f(Eb[rq][n * 16 + lr]);
                else sval = -1e9f;
                sc[n][j] = sval;
                tmax[j] = fmaxf(tmax[j], sval);
            }
        }
        float pscale[4];
        for (int j = 0; j < 4; j++) {
            float tm = tmax[j];
            tm = fmaxf(tm, __shfl_xor(tm, 1));
            tm = fmaxf(tm, __shfl_xor(tm, 2));
            tm = fmaxf(tm, __shfl_xor(tm, 4));
            tm = fmaxf(tm, __shfl_xor(tm, 8));
            const float mnew = fmaxf(m_run[j], tm);
            pscale[j] = __expf(m_run[j] - mnew);
            m_run[j] = mnew;
            l_run[j] *= pscale[j];
        }
        float psum[4] = {0.f, 0.f, 0.f, 0.f};
        for (int n = 0; n < 4; n++) {
            for (int j = 0; j < 4; j++) {
                const float p = __expf(sc[n][j] - m_run[j]);
                psum[j] += p;
                const int row = g * 4 + j;
                Ps[w][row][SW(row, n * 2 + (lr >> 3)) + (lr & 7)] = f2bf(p);
            }
        }
        for (int j = 0; j < 4; j++) {
            float s = psum[j];
            s += __shfl_xor(s, 1); s += __shfl_xor(s, 2);
            s += __shfl_xor(s, 4); s += __shfl_xor(s, 8);
            l_run[j] += s;
            for (int n2 = 0; n2 < 4; n2++) acc[n2][j] *= pscale[j];
        }
        const bf16x8 pa0 = *reinterpret_cast<const bf16x8*>(&Ps[w][lr][SW(lr, g)]);
        const bf16x8 pa1 = *reinterpret_cast<const bf16x8*>(&Ps[w][lr][SW(lr, 4 + g)]);
        for (int n2 = 0; n2 < 4; n2++) {
            const int r = n2 * 16 + lr;
            const bf16x8 vb0 = *reinterpret_cast<const bf16x8*>(&Vs[r][SW(r, g)]);
            const bf16x8 vb1 = *reinterpret_cast<const bf16x8*>(&Vs[r][SW(r, 4 + g)]);
            acc[n2] = __builtin_amdgcn_mfma_f32_16x16x32_bf16(pa0, vb0, acc[n2], 0, 0, 0);
            acc[n2] = __builtin_amdgcn_mfma_f32_16x16x32_bf16(pa1, vb1, acc[n2], 0, 0, 0);
        }
    }
    // ---- partial epilogue ----
    const size_t prow = (size_t)sp * BHS + (size_t)bh * S_;
    for (int j = 0; j < 4; j++) {
        const int qg = q0 + w * 16 + g * 4 + j;
        for (int n2 = 0; n2 < 4; n2++)
            pacc[(prow + qg) * 64 + n2 * 16 + lr] = acc[n2][j];
        if (lr == 0) { float2 v; v.x = m_run[j]; v.y = l_run[j]; pml[prow + qg] = v; }
    }
}

// ---------------- combine partials -> attnb bf16 [b][q][768] ----------------
__global__ __launch_bounds__(256) void attn_combine_kernel(
    const float* __restrict__ pacc, const float2* __restrict__ pml,
    unsigned short* __restrict__ attnb)
{
    const int idx = (blockIdx.x * 256 + threadIdx.x) * 4;  // grid 1536 covers BHS*64
    const int r = idx >> 6, d = idx & 63;
    const float2 ml0 = pml[r];
    const float2 ml1 = pml[BHS + r];
    const float M = fmaxf(ml0.x, ml1.x);
    const float w0 = __expf(ml0.x - M), w1 = __expf(ml1.x - M);
    const float L = ml0.y * w0 + ml1.y * w1;
    const float inv = (L > 0.f) ? 1.f / L : 0.f;
    const float4 a0 = *reinterpret_cast<const float4*>(&pacc[(size_t)r * 64 + d]);
    const float4 a1 = *reinterpret_cast<const float4*>(&pacc[((size_t)BHS + r) * 64 + d]);
    const int bh = r >> 10, q = r & 1023;
    const int b = bh / H_, h = bh - b * H_;
    ushort4 o;
    o.x = f2bf((a0.x * w0 + a1.x * w1) * inv);
    o.y = f2bf((a0.y * w0 + a1.y * w1) * inv);
    o.z = f2bf((a0.z * w0 + a1.z * w1) * inv);
    o.w = f2bf((a0.w * w0 + a1.w * w1) * inv);
    *reinterpret_cast<ushort4*>(&attnb[((size_t)(b * S_ + q)) * D_ + h * HD_ + d]) = o;
}

extern "C" void kernel_launch(void* const* d_in, const int* in_sizes, int n_in,
                              void* d_out, int out_size, void* d_ws, size_t ws_size,
                              hipStream_t stream)
{
    const float* x    = (const float*)d_in[0];
    const void*  adj  = d_in[1];
    const float* ea   = (const float*)d_in[2];
    const int*   ei   = (const int*)d_in[3];
    const float* g1   = (const float*)d_in[4];
    const float* bn1  = (const float*)d_in[5];
    const float* Wq   = (const float*)d_in[6];
    const float* bq   = (const float*)d_in[7];
    const float* Wk   = (const float*)d_in[8];
    const float* bk   = (const float*)d_in[9];
    const float* Wv   = (const float*)d_in[10];
    const float* bv   = (const float*)d_in[11];
    const float* Wo   = (const float*)d_in[12];
    const float* bo   = (const float*)d_in[13];
    const float* g2   = (const float*)d_in[14];
    const float* bn2  = (const float*)d_in[15];
    const float* W1   = (const float*)d_in[16];
    const float* mb1  = (const float*)d_in[17];
    const float* W2   = (const float*)d_in[18];
    const float* mb2  = (const float*)d_in[19];
    const float* epW1 = (const float*)d_in[20];
    const float* epb1 = (const float*)d_in[21];
    const float* epW2 = (const float*)d_in[22];
    const float* epb2 = (const float*)d_in[23];

    char* ws = (char*)d_ws;
    size_t off = 0;
    auto carve = [&](size_t bytes) -> void* {
        void* p = ws + off;
        off += (bytes + 255) & ~(size_t)255;
        return p;
    };
    unsigned short* wqkvt = (unsigned short*)carve((size_t)QS_ * D_ * 2);
    unsigned short* wot   = (unsigned short*)carve((size_t)D_ * D_ * 2);
    unsigned short* w1t   = (unsigned short*)carve((size_t)FF_ * D_ * 2);
    unsigned short* w2t   = (unsigned short*)carve((size_t)D_ * FF_ * 2);
    float*          bqkv  = (float*)carve((size_t)QS_ * 4);
    float*          proj  = (float*)carve((size_t)E_ * H_ * 4);
    int*            winner= (int*)carve((size_t)S_ * S_ * 4);
    unsigned short* ebias = (unsigned short*)carve((size_t)H_ * S_ * S_ * 2);  // 25.2 MB, reused as W2 partials
    unsigned int*   mpk   = (unsigned int*)carve((size_t)B_ * S_ * 32 * 4);
    unsigned short* nxb   = (unsigned short*)carve((size_t)B_ * S_ * D_ * 2);  // reused as ln2b
    unsigned short* attnb = (unsigned short*)carve((size_t)B_ * S_ * D_ * 2);
    unsigned short* qkv   = (unsigned short*)carve((size_t)B_ * S_ * QS_ * 2);
    unsigned short* vtb   = (unsigned short*)carve((size_t)B_ * S_ * D_ * 2);
    float*          x2f   = (float*)carve((size_t)B_ * S_ * D_ * 4);
    float*          pacc  = (float*)carve((size_t)NSPLIT * BHS * 64 * 4);      // 12.6 MB
    float2*         pml   = (float2*)carve((size_t)NSPLIT * BHS * 8);
    unsigned short* ln2b = nxb;
    unsigned short* hb   = qkv;           // [2048][3072] bf16 aliases qkv+vtb (dead after attn)
    float*          pw2  = (float*)ebias; // W2 split-K partials alias ebias (dead after attn)

    const int M = B_ * S_;  // 2048

    hipMemsetAsync(winner, 0xFF, (size_t)S_ * S_ * 4, stream);

    // all weight transposes + bias concat (1 launch)
    wtrans_all_kernel<<<dim3(96, 24, 6), 256, 0, stream>>>(
        Wq, Wk, Wv, Wo, W1, W2, wqkvt, wot, w1t, w2t, bq, bk, bv, bqkv);

    // LN1
    ln_kernel<<<M, 256, 0, stream>>>(x, g1, bn1, nxb);

    // fused QKV (bf16 out, Q cols scaled by 0.125)
    gemm128_kernel<false, true><<<dim3(QS_ / 128, M / 128), 256, 0, stream>>>(
        nxb, wqkvt, bqkv, qkv, M, QS_, D_, 768);

    // V transpose
    vtrans_kernel<<<dim3(S_ / 64, H_, B_), 256, 0, stream>>>(qkv, vtb);

    // edge bias pipeline
    edge_proj_scatter_kernel<<<(E_ * H_) / 256, 256, 0, stream>>>(
        ea, epW1, epb1, epW2, epb2, ei, proj, winner);
    ebias_kernel<<<S_, 256, 0, stream>>>(winner, proj, ebias);
    maskpack_kernel<<<dim3(S_, B_), 256, 0, stream>>>(adj, mpk);

    // attention (KV-split x2) + combine
    attn_mfma_kernel<<<dim3(16 * NSPLIT, H_, B_), 256, 0, stream>>>(
        qkv, vtb, ebias, mpk, pacc, pml);
    attn_combine_kernel<<<(BHS * 64) / 1024, 256, 0, stream>>>(pacc, pml, attnb);

    // Wo + residual(x) -> x2 (f32)
    gemm_kernel<true, false><<<dim3(D_ / 64, M / 64), 256, 0, stream>>>(
        attnb, wot, bo, x, x2f, M, D_, D_);

    // LN2
    ln_kernel<<<M, 256, 0, stream>>>(x2f, g2, bn2, ln2b);

    // MLP
    gemm128_kernel<true, true><<<dim3(FF_ / 128, M / 128), 256, 0, stream>>>(
        ln2b, w1t, mb1, hb, M, FF_, D_, 0);
    gemm_splitk_kernel<<<dim3(D_ / 64, M / 64, 2), 256, 0, stream>>>(
        hb, w2t, pw2, M, D_, FF_, FF_ / 2);
    w2_reduce_kernel<<<(M * D_) / 1024, 256, 0, stream>>>(pw2, x2f, mb2, (float*)d_out);
}